// Round 14
// baseline (209.352 us; speedup 1.0000x reference)
//
#include <hip/hip_runtime.h>
#include <hip/hip_fp16.h>
#include <hip/hip_bf16.h>
#include <math.h>

#define L 8192
#define LOG2L 13
#define B 16
#define CIN 64
#define COUT 64
#define KK 64

#define PI_F 3.14159265358979323846f

typedef float f4v __attribute__((ext_vector_type(4)));
typedef short s8v __attribute__((ext_vector_type(8)));

// scatter swizzle for the bit-reversal permute
__device__ __forceinline__ int swz(int n) { return n ^ ((n >> 8) & 31); }
// butterfly-storage swizzle (radix-16 passes conflict-free)
__device__ __forceinline__ int PHI(int n) { return n ^ ((((n >> 5) ^ (n >> 9)) & 15) << 1); }

// native sincos (revolutions + fract range reduction)
__device__ __forceinline__ void nsincos(float ang, float* sn, float* cs) {
    float r = ang * 0.15915494309189535f;
    r = r - floorf(r);
    *sn = __builtin_amdgcn_sinf(r);
    *cs = __builtin_amdgcn_cosf(r);
}

// f32 -> bf16 bits, round-to-nearest-even
__device__ __forceinline__ unsigned short f2bf(float f) {
    unsigned u = __builtin_bit_cast(unsigned, f);
    u += 0x7FFFu + ((u >> 16) & 1u);
    return (unsigned short)(u >> 16);
}
// pack two f32 -> bf16x2 dword (round-half-up)
__device__ __forceinline__ unsigned pkbf(float a, float b) {
    unsigned ua = __builtin_bit_cast(unsigned, a) + 0x8000u;
    unsigned ub = __builtin_bit_cast(unsigned, b) + 0x8000u;
    return (ub & 0xFFFF0000u) | (ua >> 16);
}

// fused radix-4 butterfly (two radix-2 stages)
template<int INV>
__device__ __forceinline__ void bfly4(float& u0r, float& u0i, float& u1r, float& u1i,
                                      float& v0r, float& v0i, float& v1r, float& v1i,
                                      float w1r, float w1i, float w2r, float w2i) {
    float A0r = u0r + v0r, A0i = u0i + v0i;
    float t0r = u0r - v0r, t0i = u0i - v0i;
    float B0r = t0r * w1r - t0i * w1i, B0i = t0r * w1i + t0i * w1r;
    float A1r = u1r + v1r, A1i = u1i + v1i;
    float t1r = u1r - v1r, t1i = u1i - v1i;
    float wr = t1r * w1r - t1i * w1i, wi = t1r * w1i + t1i * w1r;
    float B1r = INV ? -wi : wi;
    float B1i = INV ? wr : -wr;
    u0r = A0r + A1r; u0i = A0i + A1i;
    float d0r = A0r - A1r, d0i = A0i - A1i;
    u1r = d0r * w2r - d0i * w2i; u1i = d0r * w2i + d0i * w2r;
    v0r = B0r + B1r; v0i = B0i + B1i;
    float d1r = B0r - B1r, d1i = B0i - B1i;
    v1r = d1r * w2r - d1i * w2i; v1i = d1r * w2i + d1i * w2r;
}

// radix-16 on 16 register points; (wc,ws) = e^{∓i pi j1/(8 len2)}
template<int INV>
__device__ __forceinline__ void radix16(float* xr, float* xi, float wc, float ws) {
    const float C8 = 0.9238795325112867f, S8 = 0.3826834323650898f, C4 = 0.7071067811865476f;
    float e1r = C8, e1i = INV ? S8 : -S8;
    float e2r = C4, e2i = INV ? C4 : -C4;
    float e3r = S8, e3i = INV ? C8 : -C8;
    float a1r[4], a1i[4], a2r[4], a2i[4];
    a1r[0] = wc;                    a1i[0] = ws;
    a1r[1] = wc * e1r - ws * e1i;   a1i[1] = wc * e1i + ws * e1r;
    a1r[2] = wc * e2r - ws * e2i;   a1i[2] = wc * e2i + ws * e2r;
    a1r[3] = wc * e3r - ws * e3i;   a1i[3] = wc * e3i + ws * e3r;
#pragma unroll
    for (int q = 0; q < 4; ++q) {
        a2r[q] = a1r[q] * a1r[q] - a1i[q] * a1i[q];
        a2i[q] = 2.f * a1r[q] * a1i[q];
    }
    float b1r = a2r[0] * a2r[0] - a2i[0] * a2i[0], b1i = 2.f * a2r[0] * a2i[0];
    float b2r = b1r * b1r - b1i * b1i, b2i = 2.f * b1r * b1i;
#pragma unroll
    for (int q = 0; q < 4; ++q)
        bfly4<INV>(xr[q], xi[q], xr[q + 4], xi[q + 4], xr[q + 8], xi[q + 8],
                   xr[q + 12], xi[q + 12], a1r[q], a1i[q], a2r[q], a2i[q]);
#pragma unroll
    for (int c = 0; c < 4; ++c)
        bfly4<INV>(xr[4 * c], xi[4 * c], xr[4 * c + 1], xi[4 * c + 1],
                   xr[4 * c + 2], xi[4 * c + 2], xr[4 * c + 3], xi[4 * c + 3],
                   b1r, b1i, b2r, b2i);
}

// ---------------- kernel 1: partial per-batch min/max of |x| ----------------
__global__ __launch_bounds__(256) void k_reduce1(const float* __restrict__ xr,
                                                 const float* __restrict__ xi,
                                                 float* __restrict__ pmin,
                                                 float* __restrict__ pmax) {
    int bid = blockIdx.x;
    int batch = bid >> 6, slice = bid & 63;
    size_t base = (size_t)batch * CIN * L + (size_t)slice * L;
    int tid = threadIdx.x;
    float mn = 3.4e38f, mx = 0.0f;
    for (int r = 0; r < 32; ++r) {
        int idx = r * 256 + tid;
        float a = xr[base + idx], b = xi[base + idx];
        float m = sqrtf(a * a + b * b);
        mn = fminf(mn, m);
        mx = fmaxf(mx, m);
    }
    __shared__ float smn[4], smx[4];
    for (int off = 32; off >= 1; off >>= 1) {
        mn = fminf(mn, __shfl_down(mn, off));
        mx = fmaxf(mx, __shfl_down(mx, off));
    }
    int wave = tid >> 6;
    if ((tid & 63) == 0) { smn[wave] = mn; smx[wave] = mx; }
    __syncthreads();
    if (tid == 0) {
        for (int w = 1; w < 4; ++w) { mn = fminf(mn, smn[w]); mx = fmaxf(mx, smx[w]); }
        pmin[bid] = mn;
        pmax[bid] = mx;
    }
}

// ---------------- kernel 2: final min/max ----------------
__global__ __launch_bounds__(64) void k_reduce2(const float* __restrict__ pmin,
                                                const float* __restrict__ pmax,
                                                float* __restrict__ mmin,
                                                float* __restrict__ mmax) {
    int b = blockIdx.x, t = threadIdx.x;
    float mn = pmin[b * 64 + t], mx = pmax[b * 64 + t];
    for (int off = 32; off >= 1; off >>= 1) {
        mn = fminf(mn, __shfl_down(mn, off));
        mx = fmaxf(mx, __shfl_down(mx, off));
    }
    if (t == 0) { mmin[b] = mn; mmax[b] = mx; }
}

// ---------------- kernel 3: kernel FFT stats, B-FRAGMENT-PACKED tables ----------------
__global__ __launch_bounds__(64) void k_kstats(const float* __restrict__ kr,
                                               const float* __restrict__ ki,
                                               float* __restrict__ Pmag,
                                               float* __restrict__ Pph) {
    int row = blockIdx.x;   // io*64 + jn
    int k = threadIdx.x;
    __shared__ float sr[64], si[64];
    sr[k] = kr[row * 64 + k];
    si[k] = ki[row * 64 + k];
    __syncthreads();
    float ar = 0.f, ai = 0.f;
    for (int n = 0; n < 64; ++n) {
        int m = (n * k) & 63;
        float ang = -2.0f * PI_F * (float)m * (1.0f / 64.0f);
        float s, c;
        __sincosf(ang, &s, &c);
        ar += sr[n] * c - si[n] * s;
        ai += sr[n] * s + si[n] * c;
    }
    float mag = sqrtf(ar * ar + ai * ai);
    float ph = atan2f(ai, ar);
    int io = row >> 6, jn = row & 63;
    int ic = io >> 4, l15 = io & 15;
    int jc = jn >> 5, hi = (jn >> 3) & 3, e = jn & 7;
    int lane = hi * 16 + l15;
    size_t off = (size_t)k * 4096 + (ic * 2 + jc) * 512 + lane * 8 + e;
    Pmag[off] = mag;
    Pph[off] = ph;
    if (k == 63) {
        Pmag[off + 4096] = mag;
        Pph[off + 4096] = ph;
    }
}

// ---------------- kernel 4: coupling + stage0-in-regs + 3 radix-16 passes + permute ----------------
// x_fft written as interleaved bf16-pair dwords in p-blocked layout:
// X[pblk=512][row=1024][16 p], dword = R | I<<16, natural-order p = pblk*16+pi.
__global__ __launch_bounds__(512) void k_fwd(const float* __restrict__ xr,
                                             const float* __restrict__ xi,
                                             const float* __restrict__ mmin_,
                                             const float* __restrict__ mmax_,
                                             unsigned* __restrict__ Xd) {
    __shared__ float sRe[L];
    __shared__ float sIm[L];
    int row = blockIdx.x;          // b*64 + j
    int b = row >> 6;
    int tid = threadIdx.x;
    float mmin = mmin_[b], mmax = mmax_[b];
    float span = mmax - mmin;
    float invden = 1.0f / (span + 1e-10f);
    size_t base = (size_t)row * L;

    float vr[16], vi[16];
#pragma unroll
    for (int r = 0; r < 16; ++r) {
        int idx = r * 512 + tid;
        float a = xr[base + idx], c = xi[base + idx];
        float m = sqrtf(a * a + c * c);
        float xn = (m - mmin) * invden;
#pragma unroll
        for (int it = 0; it < 5; ++it) xn = 3.8f * xn * (1.0f - xn);
        float mc = xn * span + mmin;
        float scale = (m > 0.0f) ? (mc / m) : 0.0f;
        vr[r] = a * scale;
        vi[r] = c * scale;
    }
    // stage 0 (len 4096) in registers
#pragma unroll
    for (int r = 0; r < 8; ++r) {
        float sn, cs;
        nsincos(-PI_F * (float)(r * 512 + tid) * (1.0f / 4096.0f), &sn, &cs);
        float ar = vr[r], ai = vi[r], br = vr[r + 8], bi = vi[r + 8];
        vr[r] = ar + br; vi[r] = ai + bi;
        float dr = ar - br, di = ai - bi;
        vr[r + 8] = dr * cs - di * sn;
        vi[r + 8] = dr * sn + di * cs;
    }
#pragma unroll
    for (int r = 0; r < 16; ++r) {
        int a = PHI(r * 512 + tid);
        sRe[a] = vr[r]; sIm[a] = vi[r];
    }
    __syncthreads();

    // pass A: stages 1-4, len2=256
    {
        int j1 = tid & 255, bA = (tid >> 8) << 12;
#pragma unroll
        for (int m = 0; m < 16; ++m) {
            int a = PHI(bA + j1 + (m << 8));
            vr[m] = sRe[a]; vi[m] = sIm[a];
        }
        float sn, cs;
        nsincos(-PI_F * (float)j1 * (1.0f / 2048.0f), &sn, &cs);
        radix16<0>(vr, vi, cs, sn);
#pragma unroll
        for (int m = 0; m < 16; ++m) {
            int a = PHI(bA + j1 + (m << 8));
            sRe[a] = vr[m]; sIm[a] = vi[m];
        }
    }
    __syncthreads();
    // pass B: stages 5-8, len2=16
    {
        int j1 = tid & 15, bB = (tid >> 4) << 8;
#pragma unroll
        for (int m = 0; m < 16; ++m) {
            int a = PHI(bB + j1 + (m << 4));
            vr[m] = sRe[a]; vi[m] = sIm[a];
        }
        float sn, cs;
        nsincos(-PI_F * (float)j1 * (1.0f / 128.0f), &sn, &cs);
        radix16<0>(vr, vi, cs, sn);
#pragma unroll
        for (int m = 0; m < 16; ++m) {
            int a = PHI(bB + j1 + (m << 4));
            sRe[a] = vr[m]; sIm[a] = vi[m];
        }
    }
    __syncthreads();
    // pass C: stages 9-12, len2=1
    {
        float2* f2R = (float2*)sRe;
        float2* f2I = (float2*)sIm;
#pragma unroll
        for (int m = 0; m < 8; ++m) {
            int a = PHI(tid * 16 + 2 * m) >> 1;
            float2 vR = f2R[a], vI = f2I[a];
            vr[2 * m] = vR.x; vr[2 * m + 1] = vR.y;
            vi[2 * m] = vI.x; vi[2 * m + 1] = vI.y;
        }
        radix16<0>(vr, vi, 1.0f, 0.0f);
#pragma unroll
        for (int m = 0; m < 8; ++m) {
            int a = PHI(tid * 16 + 2 * m) >> 1;
            f2R[a] = make_float2(vr[2 * m], vr[2 * m + 1]);
            f2I[a] = make_float2(vi[2 * m], vi[2 * m + 1]);
        }
    }
    __syncthreads();

    // bitrev permute: read linear (PHI layout) -> scatter to swz layout
#pragma unroll
    for (int r = 0; r < 16; ++r) {
        int a = PHI(r * 512 + tid);
        vr[r] = sRe[a]; vi[r] = sIm[a];
    }
    __syncthreads();
#pragma unroll
    for (int r = 0; r < 16; ++r) {
        int idx = r * 512 + tid;
        int n = (int)(__brev((unsigned)idx) >> 19);
        int a = swz(n);
        sRe[a] = vr[r]; sIm[a] = vi[r];
    }
    __syncthreads();

    // pack (R,I) per p, write this thread's 16-p block (64B full line per row)
    {
        unsigned o16[16];
        int mask = (tid >> 4) & 31;
#pragma unroll
        for (int pi = 0; pi < 16; ++pi) {
            int a = (tid * 16 + pi) ^ mask;   // == swz(tid*16+pi)
            o16[pi] = ((unsigned)f2bf(sIm[a]) << 16) | f2bf(sRe[a]);
        }
        size_t ob = (size_t)tid * 16384 + (size_t)row * 16;
#pragma unroll
        for (int k = 0; k < 4; ++k)
            *(uint4*)&Xd[ob + 4 * k] = make_uint4(o16[4 * k], o16[4 * k + 1],
                                                  o16[4 * k + 2], o16[4 * k + 3]);
    }
}

// ---------------- kernel 5: MFMA complex GEMM over frequencies ----------------
// Block = one 16-p window; x-tile read as ONE dense 64KB contiguous chunk
// (coalesced), transposed to 16 p-regions in LDS. 512 thr = 8 waves x 2 p.
// i0k is block-uniform (boundaries at 64+128k align to 16).
#define PBG 16
#define RSTR 1092   // dwords per p-region: 1024 rows + 4-dword gap per 64 rows; %32==4
__global__ __launch_bounds__(512) void k_gemm(const unsigned* __restrict__ X,
                                              const float* __restrict__ Pmag,
                                              const float* __restrict__ Pph,
                                              unsigned* __restrict__ outd) {
    __shared__ unsigned lds[PBG * RSTR];   // 69,888 B
    int tid = threadIdx.x;
    int bid = blockIdx.x;   // 512
    int pwin = ((bid & 7) << 6) + (bid >> 3);   // XCD-contiguous p ranges
    int p0 = pwin * PBG;
    const unsigned* src = X + (size_t)pwin * 16384;

    // stage: dense coalesced reads, transpose into p-regions
#pragma unroll
    for (int k = 0; k < 8; ++k) {
        int u = k * 512 + tid;              // uint4 index in 64KB chunk
        uint4 v = *(const uint4*)&src[(size_t)u * 4];
        int row = u >> 2;
        int pi0 = (u & 3) * 4;
        int gr = row + ((row >> 6) << 2);
        lds[(pi0 + 0) * RSTR + gr] = v.x;
        lds[(pi0 + 1) * RSTR + gr] = v.y;
        lds[(pi0 + 2) * RSTR + gr] = v.z;
        lds[(pi0 + 3) * RSTR + gr] = v.w;
    }
    __syncthreads();

    int lane = tid & 63, wid = tid >> 6;
    int l15 = lane & 15, l4 = lane >> 4;

    int pA = p0 + wid * 2;
    float posA = ((float)pA + 0.5f) * (1.0f / 128.0f) - 0.5f;
    posA = fmaxf(posA, 0.0f);
    int i0k = (int)posA;
    bool clampv = (i0k >= KK - 1);
    float wq[2];
#pragma unroll
    for (int q = 0; q < 2; ++q) {
        float pos = ((float)(pA + q) + 0.5f) * (1.0f / 128.0f) - 0.5f;
        pos = fmaxf(pos, 0.0f);
        wq[q] = clampv ? 0.0f : (pos - (float)i0k);
    }
    const float* mb0 = Pmag + (size_t)i0k * 4096;
    const float* pb0 = Pph + (size_t)i0k * 4096;

#pragma unroll
    for (int q = 0; q < 2; ++q) {
        int pp = wid * 2 + q;
        float w = wq[q];
        f4v aR[4], aI[4];
#pragma unroll
        for (int ic = 0; ic < 4; ++ic) { aR[ic] = (f4v)0.0f; aI[ic] = (f4v)0.0f; }

#pragma unroll
        for (int jc = 0; jc < 2; ++jc) {
            int rb = pp * RSTR + l15 * 68 + jc * 32 + l4 * 8;
            uint4 d0 = *(const uint4*)&lds[rb];
            uint4 d1 = *(const uint4*)&lds[rb + 4];
            unsigned dwv[8] = {d0.x, d0.y, d0.z, d0.w, d1.x, d1.y, d1.z, d1.w};
            union { unsigned u[4]; s8v v; } xR, xI;
#pragma unroll
            for (int kk = 0; kk < 4; ++kk) {
                xR.u[kk] = (dwv[2 * kk] & 0xFFFFu) | (dwv[2 * kk + 1] << 16);
                xI.u[kk] = (dwv[2 * kk] >> 16) | (dwv[2 * kk + 1] & 0xFFFF0000u);
            }
#pragma unroll
            for (int ic = 0; ic < 4; ++ic) {
                int tb = (ic * 2 + jc) * 512 + lane * 8;
                float4 m0a = *(const float4*)(mb0 + tb);
                float4 m0b = *(const float4*)(mb0 + tb + 4);
                float4 m1a = *(const float4*)(mb0 + 4096 + tb);
                float4 m1b = *(const float4*)(mb0 + 4096 + tb + 4);
                float4 q0a = *(const float4*)(pb0 + tb);
                float4 q0b = *(const float4*)(pb0 + tb + 4);
                float4 q1a = *(const float4*)(pb0 + 4096 + tb);
                float4 q1b = *(const float4*)(pb0 + 4096 + tb + 4);
                float m0v[8] = {m0a.x, m0a.y, m0a.z, m0a.w, m0b.x, m0b.y, m0b.z, m0b.w};
                float m1v[8] = {m1a.x, m1a.y, m1a.z, m1a.w, m1b.x, m1b.y, m1b.z, m1b.w};
                float q0v[8] = {q0a.x, q0a.y, q0a.z, q0a.w, q0b.x, q0b.y, q0b.z, q0b.w};
                float q1v[8] = {q1a.x, q1a.y, q1a.z, q1a.w, q1b.x, q1b.y, q1b.z, q1b.w};
                float kr[8], ki[8];
#pragma unroll
                for (int e = 0; e < 8; ++e) {
                    float mm = m0v[e] + (m1v[e] - m0v[e]) * w;
                    float ph = q0v[e] + (q1v[e] - q0v[e]) * w;
                    float sn, cs;
                    nsincos(ph, &sn, &cs);
                    kr[e] = mm * cs;
                    ki[e] = mm * sn;
                }
                union { unsigned u[4]; s8v v; } kR, kIp, kIn;
#pragma unroll
                for (int t = 0; t < 4; ++t) {
                    kR.u[t] = pkbf(kr[2 * t], kr[2 * t + 1]);
                    kIp.u[t] = pkbf(ki[2 * t], ki[2 * t + 1]);
                    kIn.u[t] = kIp.u[t] ^ 0x80008000u;
                }
                aR[ic] = __builtin_amdgcn_mfma_f32_16x16x32_bf16(xR.v, kR.v, aR[ic], 0, 0, 0);
                aR[ic] = __builtin_amdgcn_mfma_f32_16x16x32_bf16(xI.v, kIn.v, aR[ic], 0, 0, 0);
                aI[ic] = __builtin_amdgcn_mfma_f32_16x16x32_bf16(xR.v, kIp.v, aI[ic], 0, 0, 0);
                aI[ic] = __builtin_amdgcn_mfma_f32_16x16x32_bf16(xI.v, kR.v, aI[ic], 0, 0, 0);
            }
        }

        // overlay out[b*64+i] into this wave's own (now dead) region pp
#pragma unroll
        for (int ic = 0; ic < 4; ++ic)
#pragma unroll
            for (int e = 0; e < 4; ++e) {
                int ro = (l4 * 4 + e) * 64 + ic * 16 + l15;   // b*64 + i
                int gro = ro + ((ro >> 6) << 2);
                lds[pp * RSTR + gro] =
                    ((unsigned)f2bf(aI[ic][e]) << 16) | f2bf(aR[ic][e]);
            }
    }
    __syncthreads();

    // store: thread handles rows {tid, tid+512}; 64B contiguous per row
#pragma unroll
    for (int rr = 0; rr < 2; ++rr) {
        int row = rr * 512 + tid;
        int gr = row + ((row >> 6) << 2);
        unsigned o[16];
#pragma unroll
        for (int pi = 0; pi < 16; ++pi) o[pi] = lds[pi * RSTR + gr];
        size_t ob = (size_t)row * 8192 + p0;
#pragma unroll
        for (int k = 0; k < 4; ++k)
            *(uint4*)&outd[ob + 4 * k] = make_uint4(o[4 * k], o[4 * k + 1],
                                                    o[4 * k + 2], o[4 * k + 3]);
    }
}

// ---------------- kernel 6: inverse FFT (stage0-in-regs + 3 radix-16) + activation ----------------
__global__ __launch_bounds__(512) void k_ifft(const __hip_bfloat162* __restrict__ outfft,
                                              const float* __restrict__ alpha_,
                                              float* __restrict__ out) {
    __shared__ float sRe[L];
    __shared__ float sIm[L];
    int row = blockIdx.x;          // b*64 + i
    int tid = threadIdx.x;
    float alpha = alpha_[0];
    size_t base = (size_t)row * L;

    float vr[16], vi[16];
#pragma unroll
    for (int r = 0; r < 16; ++r) {
        __hip_bfloat162 v = outfft[base + r * 512 + tid];
        vr[r] = __bfloat162float(v.x);
        vi[r] = __bfloat162float(v.y);
    }
#pragma unroll
    for (int r = 0; r < 8; ++r) {
        float sn, cs;
        nsincos(PI_F * (float)(r * 512 + tid) * (1.0f / 4096.0f), &sn, &cs);
        float ar = vr[r], ai = vi[r], br = vr[r + 8], bi = vi[r + 8];
        vr[r] = ar + br; vi[r] = ai + bi;
        float dr = ar - br, di = ai - bi;
        vr[r + 8] = dr * cs - di * sn;
        vi[r + 8] = dr * sn + di * cs;
    }
#pragma unroll
    for (int r = 0; r < 16; ++r) {
        int a = PHI(r * 512 + tid);
        sRe[a] = vr[r]; sIm[a] = vi[r];
    }
    __syncthreads();

    // pass A
    {
        int j1 = tid & 255, bA = (tid >> 8) << 12;
#pragma unroll
        for (int m = 0; m < 16; ++m) {
            int a = PHI(bA + j1 + (m << 8));
            vr[m] = sRe[a]; vi[m] = sIm[a];
        }
        float sn, cs;
        nsincos(PI_F * (float)j1 * (1.0f / 2048.0f), &sn, &cs);
        radix16<1>(vr, vi, cs, sn);
#pragma unroll
        for (int m = 0; m < 16; ++m) {
            int a = PHI(bA + j1 + (m << 8));
            sRe[a] = vr[m]; sIm[a] = vi[m];
        }
    }
    __syncthreads();
    // pass B
    {
        int j1 = tid & 15, bB = (tid >> 4) << 8;
#pragma unroll
        for (int m = 0; m < 16; ++m) {
            int a = PHI(bB + j1 + (m << 4));
            vr[m] = sRe[a]; vi[m] = sIm[a];
        }
        float sn, cs;
        nsincos(PI_F * (float)j1 * (1.0f / 128.0f), &sn, &cs);
        radix16<1>(vr, vi, cs, sn);
#pragma unroll
        for (int m = 0; m < 16; ++m) {
            int a = PHI(bB + j1 + (m << 4));
            sRe[a] = vr[m]; sIm[a] = vi[m];
        }
    }
    __syncthreads();
    // pass C
    {
        float2* f2R = (float2*)sRe;
        float2* f2I = (float2*)sIm;
#pragma unroll
        for (int m = 0; m < 8; ++m) {
            int a = PHI(tid * 16 + 2 * m) >> 1;
            float2 vR = f2R[a], vI = f2I[a];
            vr[2 * m] = vR.x; vr[2 * m + 1] = vR.y;
            vi[2 * m] = vI.x; vi[2 * m + 1] = vI.y;
        }
        radix16<1>(vr, vi, 1.0f, 0.0f);
#pragma unroll
        for (int m = 0; m < 8; ++m) {
            int a = PHI(tid * 16 + 2 * m) >> 1;
            f2R[a] = make_float2(vr[2 * m], vr[2 * m + 1]);
            f2I[a] = make_float2(vi[2 * m], vi[2 * m + 1]);
        }
    }
    __syncthreads();

#pragma unroll
    for (int r = 0; r < 16; ++r) {
        int a = PHI(r * 512 + tid);
        vr[r] = sRe[a]; vi[r] = sIm[a];
    }
    __syncthreads();
#pragma unroll
    for (int r = 0; r < 16; ++r) {
        int idx = r * 512 + tid;
        int n = (int)(__brev((unsigned)idx) >> 19);
        int a = swz(n);
        sRe[a] = vr[r]; sIm[a] = vi[r];
    }
    __syncthreads();

    const float invN = 1.0f / (float)L;
#pragma unroll
    for (int rpt = 0; rpt < L / 512; ++rpt) {
        int n = rpt * 512 + tid;
        float act = sinf(alpha * (float)n);
        out[base + n] = sRe[swz(n)] * act * invN;
    }
}

// ---------------- launch ----------------
extern "C" void kernel_launch(void* const* d_in, const int* in_sizes, int n_in,
                              void* d_out, int out_size, void* d_ws, size_t ws_size,
                              hipStream_t stream) {
    const float* xr = (const float*)d_in[0];
    const float* xi = (const float*)d_in[1];
    const float* kr = (const float*)d_in[2];
    const float* ki = (const float*)d_in[3];
    const float* alpha = (const float*)d_in[4];
    float* out = (float*)d_out;

    char* ws = (char*)d_ws;
    size_t OFFT_BYTES = (size_t)B * COUT * L * 4;
    size_t TBL_BYTES = (size_t)65 * 4096 * 4;
    unsigned* outfft_d = (unsigned*)ws;
    float* Pmag = (float*)(ws + OFFT_BYTES);
    float* Pph  = (float*)(ws + OFFT_BYTES + TBL_BYTES);
    float* pmin = (float*)(ws + OFFT_BYTES + 2 * TBL_BYTES);
    float* pmax = pmin + 1024;
    float* mmin = pmax + 1024;
    float* mmax = mmin + 16;

    unsigned* Xd = (unsigned*)d_out;   // p-blocked pair-dword x_fft; overwritten by k_ifft

    hipLaunchKernelGGL(k_reduce1, dim3(1024), dim3(256), 0, stream, xr, xi, pmin, pmax);
    hipLaunchKernelGGL(k_reduce2, dim3(16), dim3(64), 0, stream, pmin, pmax, mmin, mmax);
    hipLaunchKernelGGL(k_kstats, dim3(4096), dim3(64), 0, stream, kr, ki, Pmag, Pph);
    hipLaunchKernelGGL(k_fwd, dim3(1024), dim3(512), 0, stream, xr, xi, mmin, mmax, Xd);
    hipLaunchKernelGGL(k_gemm, dim3(512), dim3(512), 0, stream, Xd, Pmag, Pph, outfft_d);
    hipLaunchKernelGGL(k_ifft, dim3(1024), dim3(512), 0, stream,
                       (const __hip_bfloat162*)outfft_d, alpha, out);
}

// Round 15
// 174.588 us; speedup vs baseline: 1.1991x; 1.1991x over previous
//
#include <hip/hip_runtime.h>
#include <hip/hip_fp16.h>
#include <hip/hip_bf16.h>
#include <math.h>

#define L 8192
#define LOG2L 13
#define B 16
#define CIN 64
#define COUT 64
#define KK 64

#define PI_F 3.14159265358979323846f

typedef float f4v __attribute__((ext_vector_type(4)));
typedef short s8v __attribute__((ext_vector_type(8)));

// scatter swizzle for the bit-reversal permute
__device__ __forceinline__ int swz(int n) { return n ^ ((n >> 8) & 31); }
// butterfly-storage swizzle (radix-16 passes conflict-free)
__device__ __forceinline__ int PHI(int n) { return n ^ ((((n >> 5) ^ (n >> 9)) & 15) << 1); }

// native sincos (revolutions + fract range reduction)
__device__ __forceinline__ void nsincos(float ang, float* sn, float* cs) {
    float r = ang * 0.15915494309189535f;
    r = r - floorf(r);
    *sn = __builtin_amdgcn_sinf(r);
    *cs = __builtin_amdgcn_cosf(r);
}

// f32 -> bf16 bits, round-to-nearest-even
__device__ __forceinline__ unsigned short f2bf(float f) {
    unsigned u = __builtin_bit_cast(unsigned, f);
    u += 0x7FFFu + ((u >> 16) & 1u);
    return (unsigned short)(u >> 16);
}
// pack two f32 -> bf16x2 dword (round-half-up)
__device__ __forceinline__ unsigned pkbf(float a, float b) {
    unsigned ua = __builtin_bit_cast(unsigned, a) + 0x8000u;
    unsigned ub = __builtin_bit_cast(unsigned, b) + 0x8000u;
    return (ub & 0xFFFF0000u) | (ua >> 16);
}

// fused radix-4 butterfly (two radix-2 stages)
template<int INV>
__device__ __forceinline__ void bfly4(float& u0r, float& u0i, float& u1r, float& u1i,
                                      float& v0r, float& v0i, float& v1r, float& v1i,
                                      float w1r, float w1i, float w2r, float w2i) {
    float A0r = u0r + v0r, A0i = u0i + v0i;
    float t0r = u0r - v0r, t0i = u0i - v0i;
    float B0r = t0r * w1r - t0i * w1i, B0i = t0r * w1i + t0i * w1r;
    float A1r = u1r + v1r, A1i = u1i + v1i;
    float t1r = u1r - v1r, t1i = u1i - v1i;
    float wr = t1r * w1r - t1i * w1i, wi = t1r * w1i + t1i * w1r;
    float B1r = INV ? -wi : wi;
    float B1i = INV ? wr : -wr;
    u0r = A0r + A1r; u0i = A0i + A1i;
    float d0r = A0r - A1r, d0i = A0i - A1i;
    u1r = d0r * w2r - d0i * w2i; u1i = d0r * w2i + d0i * w2r;
    v0r = B0r + B1r; v0i = B0i + B1i;
    float d1r = B0r - B1r, d1i = B0i - B1i;
    v1r = d1r * w2r - d1i * w2i; v1i = d1r * w2i + d1i * w2r;
}

// radix-16 on 16 register points; (wc,ws) = e^{∓i pi j1/(8 len2)}
template<int INV>
__device__ __forceinline__ void radix16(float* xr, float* xi, float wc, float ws) {
    const float C8 = 0.9238795325112867f, S8 = 0.3826834323650898f, C4 = 0.7071067811865476f;
    float e1r = C8, e1i = INV ? S8 : -S8;
    float e2r = C4, e2i = INV ? C4 : -C4;
    float e3r = S8, e3i = INV ? C8 : -C8;
    float a1r[4], a1i[4], a2r[4], a2i[4];
    a1r[0] = wc;                    a1i[0] = ws;
    a1r[1] = wc * e1r - ws * e1i;   a1i[1] = wc * e1i + ws * e1r;
    a1r[2] = wc * e2r - ws * e2i;   a1i[2] = wc * e2i + ws * e2r;
    a1r[3] = wc * e3r - ws * e3i;   a1i[3] = wc * e3i + ws * e3r;
#pragma unroll
    for (int q = 0; q < 4; ++q) {
        a2r[q] = a1r[q] * a1r[q] - a1i[q] * a1i[q];
        a2i[q] = 2.f * a1r[q] * a1i[q];
    }
    float b1r = a2r[0] * a2r[0] - a2i[0] * a2i[0], b1i = 2.f * a2r[0] * a2i[0];
    float b2r = b1r * b1r - b1i * b1i, b2i = 2.f * b1r * b1i;
#pragma unroll
    for (int q = 0; q < 4; ++q)
        bfly4<INV>(xr[q], xi[q], xr[q + 4], xi[q + 4], xr[q + 8], xi[q + 8],
                   xr[q + 12], xi[q + 12], a1r[q], a1i[q], a2r[q], a2i[q]);
#pragma unroll
    for (int c = 0; c < 4; ++c)
        bfly4<INV>(xr[4 * c], xi[4 * c], xr[4 * c + 1], xi[4 * c + 1],
                   xr[4 * c + 2], xi[4 * c + 2], xr[4 * c + 3], xi[4 * c + 3],
                   b1r, b1i, b2r, b2i);
}

// ---------------- kernel 1: partial per-batch min/max of |x| ----------------
__global__ __launch_bounds__(256) void k_reduce1(const float* __restrict__ xr,
                                                 const float* __restrict__ xi,
                                                 float* __restrict__ pmin,
                                                 float* __restrict__ pmax) {
    int bid = blockIdx.x;
    int batch = bid >> 6, slice = bid & 63;
    size_t base = (size_t)batch * CIN * L + (size_t)slice * L;
    int tid = threadIdx.x;
    float mn = 3.4e38f, mx = 0.0f;
    for (int r = 0; r < 32; ++r) {
        int idx = r * 256 + tid;
        float a = xr[base + idx], b = xi[base + idx];
        float m = sqrtf(a * a + b * b);
        mn = fminf(mn, m);
        mx = fmaxf(mx, m);
    }
    __shared__ float smn[4], smx[4];
    for (int off = 32; off >= 1; off >>= 1) {
        mn = fminf(mn, __shfl_down(mn, off));
        mx = fmaxf(mx, __shfl_down(mx, off));
    }
    int wave = tid >> 6;
    if ((tid & 63) == 0) { smn[wave] = mn; smx[wave] = mx; }
    __syncthreads();
    if (tid == 0) {
        for (int w = 1; w < 4; ++w) { mn = fminf(mn, smn[w]); mx = fmaxf(mx, smx[w]); }
        pmin[bid] = mn;
        pmax[bid] = mx;
    }
}

// ---------------- kernel 2: final min/max ----------------
__global__ __launch_bounds__(64) void k_reduce2(const float* __restrict__ pmin,
                                                const float* __restrict__ pmax,
                                                float* __restrict__ mmin,
                                                float* __restrict__ mmax) {
    int b = blockIdx.x, t = threadIdx.x;
    float mn = pmin[b * 64 + t], mx = pmax[b * 64 + t];
    for (int off = 32; off >= 1; off >>= 1) {
        mn = fminf(mn, __shfl_down(mn, off));
        mx = fmaxf(mx, __shfl_down(mx, off));
    }
    if (t == 0) { mmin[b] = mn; mmax[b] = mx; }
}

// ---------------- kernel 3: kernel FFT stats, B-FRAGMENT-PACKED tables ----------------
__global__ __launch_bounds__(64) void k_kstats(const float* __restrict__ kr,
                                               const float* __restrict__ ki,
                                               float* __restrict__ Pmag,
                                               float* __restrict__ Pph) {
    int row = blockIdx.x;   // io*64 + jn
    int k = threadIdx.x;
    __shared__ float sr[64], si[64];
    sr[k] = kr[row * 64 + k];
    si[k] = ki[row * 64 + k];
    __syncthreads();
    float ar = 0.f, ai = 0.f;
    for (int n = 0; n < 64; ++n) {
        int m = (n * k) & 63;
        float ang = -2.0f * PI_F * (float)m * (1.0f / 64.0f);
        float s, c;
        __sincosf(ang, &s, &c);
        ar += sr[n] * c - si[n] * s;
        ai += sr[n] * s + si[n] * c;
    }
    float mag = sqrtf(ar * ar + ai * ai);
    float ph = atan2f(ai, ar);
    int io = row >> 6, jn = row & 63;
    int ic = io >> 4, l15 = io & 15;
    int jc = jn >> 5, hi = (jn >> 3) & 3, e = jn & 7;
    int lane = hi * 16 + l15;
    size_t off = (size_t)k * 4096 + (ic * 2 + jc) * 512 + lane * 8 + e;
    Pmag[off] = mag;
    Pph[off] = ph;
    if (k == 63) {
        Pmag[off + 4096] = mag;
        Pph[off + 4096] = ph;
    }
}

// ---------------- kernel 4: coupling + stage0-in-regs + 3 radix-16 passes + permute ----------------
// x_fft written as interleaved bf16-pair dwords in p-blocked layout:
// X[pblk=512][row=1024][16 p], dword = R | I<<16, natural-order p = pblk*16+pi.
__global__ __launch_bounds__(512) void k_fwd(const float* __restrict__ xr,
                                             const float* __restrict__ xi,
                                             const float* __restrict__ mmin_,
                                             const float* __restrict__ mmax_,
                                             unsigned* __restrict__ Xd) {
    __shared__ float sRe[L];
    __shared__ float sIm[L];
    int row = blockIdx.x;          // b*64 + j
    int b = row >> 6;
    int tid = threadIdx.x;
    float mmin = mmin_[b], mmax = mmax_[b];
    float span = mmax - mmin;
    float invden = 1.0f / (span + 1e-10f);
    size_t base = (size_t)row * L;

    float vr[16], vi[16];
#pragma unroll
    for (int r = 0; r < 16; ++r) {
        int idx = r * 512 + tid;
        float a = xr[base + idx], c = xi[base + idx];
        float m = sqrtf(a * a + c * c);
        float xn = (m - mmin) * invden;
#pragma unroll
        for (int it = 0; it < 5; ++it) xn = 3.8f * xn * (1.0f - xn);
        float mc = xn * span + mmin;
        float scale = (m > 0.0f) ? (mc / m) : 0.0f;
        vr[r] = a * scale;
        vi[r] = c * scale;
    }
    // stage 0 (len 4096) in registers
#pragma unroll
    for (int r = 0; r < 8; ++r) {
        float sn, cs;
        nsincos(-PI_F * (float)(r * 512 + tid) * (1.0f / 4096.0f), &sn, &cs);
        float ar = vr[r], ai = vi[r], br = vr[r + 8], bi = vi[r + 8];
        vr[r] = ar + br; vi[r] = ai + bi;
        float dr = ar - br, di = ai - bi;
        vr[r + 8] = dr * cs - di * sn;
        vi[r + 8] = dr * sn + di * cs;
    }
#pragma unroll
    for (int r = 0; r < 16; ++r) {
        int a = PHI(r * 512 + tid);
        sRe[a] = vr[r]; sIm[a] = vi[r];
    }
    __syncthreads();

    // pass A: stages 1-4, len2=256
    {
        int j1 = tid & 255, bA = (tid >> 8) << 12;
#pragma unroll
        for (int m = 0; m < 16; ++m) {
            int a = PHI(bA + j1 + (m << 8));
            vr[m] = sRe[a]; vi[m] = sIm[a];
        }
        float sn, cs;
        nsincos(-PI_F * (float)j1 * (1.0f / 2048.0f), &sn, &cs);
        radix16<0>(vr, vi, cs, sn);
#pragma unroll
        for (int m = 0; m < 16; ++m) {
            int a = PHI(bA + j1 + (m << 8));
            sRe[a] = vr[m]; sIm[a] = vi[m];
        }
    }
    __syncthreads();
    // pass B: stages 5-8, len2=16
    {
        int j1 = tid & 15, bB = (tid >> 4) << 8;
#pragma unroll
        for (int m = 0; m < 16; ++m) {
            int a = PHI(bB + j1 + (m << 4));
            vr[m] = sRe[a]; vi[m] = sIm[a];
        }
        float sn, cs;
        nsincos(-PI_F * (float)j1 * (1.0f / 128.0f), &sn, &cs);
        radix16<0>(vr, vi, cs, sn);
#pragma unroll
        for (int m = 0; m < 16; ++m) {
            int a = PHI(bB + j1 + (m << 4));
            sRe[a] = vr[m]; sIm[a] = vi[m];
        }
    }
    __syncthreads();
    // pass C: stages 9-12, len2=1
    {
        float2* f2R = (float2*)sRe;
        float2* f2I = (float2*)sIm;
#pragma unroll
        for (int m = 0; m < 8; ++m) {
            int a = PHI(tid * 16 + 2 * m) >> 1;
            float2 vR = f2R[a], vI = f2I[a];
            vr[2 * m] = vR.x; vr[2 * m + 1] = vR.y;
            vi[2 * m] = vI.x; vi[2 * m + 1] = vI.y;
        }
        radix16<0>(vr, vi, 1.0f, 0.0f);
#pragma unroll
        for (int m = 0; m < 8; ++m) {
            int a = PHI(tid * 16 + 2 * m) >> 1;
            f2R[a] = make_float2(vr[2 * m], vr[2 * m + 1]);
            f2I[a] = make_float2(vi[2 * m], vi[2 * m + 1]);
        }
    }
    __syncthreads();

    // bitrev permute: read linear (PHI layout) -> scatter to swz layout
#pragma unroll
    for (int r = 0; r < 16; ++r) {
        int a = PHI(r * 512 + tid);
        vr[r] = sRe[a]; vi[r] = sIm[a];
    }
    __syncthreads();
#pragma unroll
    for (int r = 0; r < 16; ++r) {
        int idx = r * 512 + tid;
        int n = (int)(__brev((unsigned)idx) >> 19);
        int a = swz(n);
        sRe[a] = vr[r]; sIm[a] = vi[r];
    }
    __syncthreads();

    // pack (R,I) per p, write this thread's 16-p block (64B full line per row)
    {
        unsigned o16[16];
        int mask = (tid >> 4) & 31;
#pragma unroll
        for (int pi = 0; pi < 16; ++pi) {
            int a = (tid * 16 + pi) ^ mask;   // == swz(tid*16+pi)
            o16[pi] = ((unsigned)f2bf(sIm[a]) << 16) | f2bf(sRe[a]);
        }
        size_t ob = (size_t)tid * 16384 + (size_t)row * 16;
#pragma unroll
        for (int k = 0; k < 4; ++k)
            *(uint4*)&Xd[ob + 4 * k] = make_uint4(o16[4 * k], o16[4 * k + 1],
                                                  o16[4 * k + 2], o16[4 * k + 3]);
    }
}

// ---------------- kernel 5: MFMA complex GEMM over frequencies ----------------
// Block = one 8-p window, 256 threads (4 waves x 2 p). X layout [512][1024][16]:
// the block reads its half of each 64B row-chunk (sibling block on same XCD reads
// the other half -> full lines at L2). No 512-thread VGPR cap -> no spills.
#define PBG 8
#define RSTR 1092   // dwords per p-region: 1024 rows + 4-dword gap per 64 rows; %32==4
__global__ __launch_bounds__(256) void k_gemm(const unsigned* __restrict__ X,
                                              const float* __restrict__ Pmag,
                                              const float* __restrict__ Pph,
                                              unsigned* __restrict__ outd) {
    __shared__ unsigned lds[PBG * RSTR];   // 34,944 B
    int tid = threadIdx.x;
    int bid = blockIdx.x;   // 1024
    int pwin = ((bid & 7) << 7) + (bid >> 3);   // XCD-contiguous p ranges; siblings adjacent
    int p0 = pwin * PBG;
    int half = pwin & 1;
    const unsigned* src = X + (size_t)(pwin >> 1) * 16384 + half * 8;

    // stage: 2 x 16B per row (dense within our half), transpose into 8 p-regions
#pragma unroll
    for (int k = 0; k < 8; ++k) {
        int u = k * 256 + tid;              // 0..2047
        int row = u >> 1;
        int g = u & 1;
        uint4 v = *(const uint4*)&src[(size_t)row * 16 + g * 4];
        int gr = row + ((row >> 6) << 2);
        int pl0 = g * 4;
        lds[(pl0 + 0) * RSTR + gr] = v.x;
        lds[(pl0 + 1) * RSTR + gr] = v.y;
        lds[(pl0 + 2) * RSTR + gr] = v.z;
        lds[(pl0 + 3) * RSTR + gr] = v.w;
    }
    __syncthreads();

    int lane = tid & 63, wid = tid >> 6;
    int l15 = lane & 15, l4 = lane >> 4;

    int pA = p0 + wid * 2;
    float posA = ((float)pA + 0.5f) * (1.0f / 128.0f) - 0.5f;
    posA = fmaxf(posA, 0.0f);
    int i0k = (int)posA;
    bool clampv = (i0k >= KK - 1);
    float wq[2];
#pragma unroll
    for (int q = 0; q < 2; ++q) {
        float pos = ((float)(pA + q) + 0.5f) * (1.0f / 128.0f) - 0.5f;
        pos = fmaxf(pos, 0.0f);
        wq[q] = clampv ? 0.0f : (pos - (float)i0k);
    }
    const float* mb0 = Pmag + (size_t)i0k * 4096;
    const float* pb0 = Pph + (size_t)i0k * 4096;

#pragma unroll
    for (int q = 0; q < 2; ++q) {
        int pp = wid * 2 + q;
        float w = wq[q];
        f4v aR[4], aI[4];
#pragma unroll
        for (int ic = 0; ic < 4; ++ic) { aR[ic] = (f4v)0.0f; aI[ic] = (f4v)0.0f; }

#pragma unroll
        for (int jc = 0; jc < 2; ++jc) {
            int rb = pp * RSTR + l15 * 68 + jc * 32 + l4 * 8;
            uint4 d0 = *(const uint4*)&lds[rb];
            uint4 d1 = *(const uint4*)&lds[rb + 4];
            unsigned dwv[8] = {d0.x, d0.y, d0.z, d0.w, d1.x, d1.y, d1.z, d1.w};
            union { unsigned u[4]; s8v v; } xR, xI;
#pragma unroll
            for (int kk = 0; kk < 4; ++kk) {
                xR.u[kk] = (dwv[2 * kk] & 0xFFFFu) | (dwv[2 * kk + 1] << 16);
                xI.u[kk] = (dwv[2 * kk] >> 16) | (dwv[2 * kk + 1] & 0xFFFF0000u);
            }
#pragma unroll
            for (int ic = 0; ic < 4; ++ic) {
                int tb = (ic * 2 + jc) * 512 + lane * 8;
                float4 m0a = *(const float4*)(mb0 + tb);
                float4 m0b = *(const float4*)(mb0 + tb + 4);
                float4 m1a = *(const float4*)(mb0 + 4096 + tb);
                float4 m1b = *(const float4*)(mb0 + 4096 + tb + 4);
                float4 q0a = *(const float4*)(pb0 + tb);
                float4 q0b = *(const float4*)(pb0 + tb + 4);
                float4 q1a = *(const float4*)(pb0 + 4096 + tb);
                float4 q1b = *(const float4*)(pb0 + 4096 + tb + 4);
                float m0v[8] = {m0a.x, m0a.y, m0a.z, m0a.w, m0b.x, m0b.y, m0b.z, m0b.w};
                float m1v[8] = {m1a.x, m1a.y, m1a.z, m1a.w, m1b.x, m1b.y, m1b.z, m1b.w};
                float q0v[8] = {q0a.x, q0a.y, q0a.z, q0a.w, q0b.x, q0b.y, q0b.z, q0b.w};
                float q1v[8] = {q1a.x, q1a.y, q1a.z, q1a.w, q1b.x, q1b.y, q1b.z, q1b.w};
                float kr[8], ki[8];
#pragma unroll
                for (int e = 0; e < 8; ++e) {
                    float mm = m0v[e] + (m1v[e] - m0v[e]) * w;
                    float ph = q0v[e] + (q1v[e] - q0v[e]) * w;
                    float sn, cs;
                    nsincos(ph, &sn, &cs);
                    kr[e] = mm * cs;
                    ki[e] = mm * sn;
                }
                union { unsigned u[4]; s8v v; } kR, kIp, kIn;
#pragma unroll
                for (int t = 0; t < 4; ++t) {
                    kR.u[t] = pkbf(kr[2 * t], kr[2 * t + 1]);
                    kIp.u[t] = pkbf(ki[2 * t], ki[2 * t + 1]);
                    kIn.u[t] = kIp.u[t] ^ 0x80008000u;
                }
                aR[ic] = __builtin_amdgcn_mfma_f32_16x16x32_bf16(xR.v, kR.v, aR[ic], 0, 0, 0);
                aR[ic] = __builtin_amdgcn_mfma_f32_16x16x32_bf16(xI.v, kIn.v, aR[ic], 0, 0, 0);
                aI[ic] = __builtin_amdgcn_mfma_f32_16x16x32_bf16(xR.v, kIp.v, aI[ic], 0, 0, 0);
                aI[ic] = __builtin_amdgcn_mfma_f32_16x16x32_bf16(xI.v, kR.v, aI[ic], 0, 0, 0);
            }
        }

        // overlay out[b*64+i] into this wave's own (now dead) region pp
#pragma unroll
        for (int ic = 0; ic < 4; ++ic)
#pragma unroll
            for (int e = 0; e < 4; ++e) {
                int ro = (l4 * 4 + e) * 64 + ic * 16 + l15;   // b*64 + i
                int gro = ro + ((ro >> 6) << 2);
                lds[pp * RSTR + gro] =
                    ((unsigned)f2bf(aI[ic][e]) << 16) | f2bf(aR[ic][e]);
            }
    }
    __syncthreads();

    // store: 8 lanes x 8 consecutive dwords per row group (proven pattern, no RMW amp)
#pragma unroll
    for (int k = 0; k < 32; ++k) {
        int row = k * 32 + (tid >> 3);
        int gr = row + ((row >> 6) << 2);
        outd[(size_t)row * 8192 + p0 + (tid & 7)] = lds[(tid & 7) * RSTR + gr];
    }
}

// ---------------- kernel 6: inverse FFT (stage0-in-regs + 3 radix-16) + activation ----------------
__global__ __launch_bounds__(512) void k_ifft(const __hip_bfloat162* __restrict__ outfft,
                                              const float* __restrict__ alpha_,
                                              float* __restrict__ out) {
    __shared__ float sRe[L];
    __shared__ float sIm[L];
    int row = blockIdx.x;          // b*64 + i
    int tid = threadIdx.x;
    float alpha = alpha_[0];
    size_t base = (size_t)row * L;

    float vr[16], vi[16];
#pragma unroll
    for (int r = 0; r < 16; ++r) {
        __hip_bfloat162 v = outfft[base + r * 512 + tid];
        vr[r] = __bfloat162float(v.x);
        vi[r] = __bfloat162float(v.y);
    }
#pragma unroll
    for (int r = 0; r < 8; ++r) {
        float sn, cs;
        nsincos(PI_F * (float)(r * 512 + tid) * (1.0f / 4096.0f), &sn, &cs);
        float ar = vr[r], ai = vi[r], br = vr[r + 8], bi = vi[r + 8];
        vr[r] = ar + br; vi[r] = ai + bi;
        float dr = ar - br, di = ai - bi;
        vr[r + 8] = dr * cs - di * sn;
        vi[r + 8] = dr * sn + di * cs;
    }
#pragma unroll
    for (int r = 0; r < 16; ++r) {
        int a = PHI(r * 512 + tid);
        sRe[a] = vr[r]; sIm[a] = vi[r];
    }
    __syncthreads();

    // pass A
    {
        int j1 = tid & 255, bA = (tid >> 8) << 12;
#pragma unroll
        for (int m = 0; m < 16; ++m) {
            int a = PHI(bA + j1 + (m << 8));
            vr[m] = sRe[a]; vi[m] = sIm[a];
        }
        float sn, cs;
        nsincos(PI_F * (float)j1 * (1.0f / 2048.0f), &sn, &cs);
        radix16<1>(vr, vi, cs, sn);
#pragma unroll
        for (int m = 0; m < 16; ++m) {
            int a = PHI(bA + j1 + (m << 8));
            sRe[a] = vr[m]; sIm[a] = vi[m];
        }
    }
    __syncthreads();
    // pass B
    {
        int j1 = tid & 15, bB = (tid >> 4) << 8;
#pragma unroll
        for (int m = 0; m < 16; ++m) {
            int a = PHI(bB + j1 + (m << 4));
            vr[m] = sRe[a]; vi[m] = sIm[a];
        }
        float sn, cs;
        nsincos(PI_F * (float)j1 * (1.0f / 128.0f), &sn, &cs);
        radix16<1>(vr, vi, cs, sn);
#pragma unroll
        for (int m = 0; m < 16; ++m) {
            int a = PHI(bB + j1 + (m << 4));
            sRe[a] = vr[m]; sIm[a] = vi[m];
        }
    }
    __syncthreads();
    // pass C
    {
        float2* f2R = (float2*)sRe;
        float2* f2I = (float2*)sIm;
#pragma unroll
        for (int m = 0; m < 8; ++m) {
            int a = PHI(tid * 16 + 2 * m) >> 1;
            float2 vR = f2R[a], vI = f2I[a];
            vr[2 * m] = vR.x; vr[2 * m + 1] = vR.y;
            vi[2 * m] = vI.x; vi[2 * m + 1] = vI.y;
        }
        radix16<1>(vr, vi, 1.0f, 0.0f);
#pragma unroll
        for (int m = 0; m < 8; ++m) {
            int a = PHI(tid * 16 + 2 * m) >> 1;
            f2R[a] = make_float2(vr[2 * m], vr[2 * m + 1]);
            f2I[a] = make_float2(vi[2 * m], vi[2 * m + 1]);
        }
    }
    __syncthreads();

#pragma unroll
    for (int r = 0; r < 16; ++r) {
        int a = PHI(r * 512 + tid);
        vr[r] = sRe[a]; vi[r] = sIm[a];
    }
    __syncthreads();
#pragma unroll
    for (int r = 0; r < 16; ++r) {
        int idx = r * 512 + tid;
        int n = (int)(__brev((unsigned)idx) >> 19);
        int a = swz(n);
        sRe[a] = vr[r]; sIm[a] = vi[r];
    }
    __syncthreads();

    const float invN = 1.0f / (float)L;
#pragma unroll
    for (int rpt = 0; rpt < L / 512; ++rpt) {
        int n = rpt * 512 + tid;
        float act = sinf(alpha * (float)n);
        out[base + n] = sRe[swz(n)] * act * invN;
    }
}

// ---------------- launch ----------------
extern "C" void kernel_launch(void* const* d_in, const int* in_sizes, int n_in,
                              void* d_out, int out_size, void* d_ws, size_t ws_size,
                              hipStream_t stream) {
    const float* xr = (const float*)d_in[0];
    const float* xi = (const float*)d_in[1];
    const float* kr = (const float*)d_in[2];
    const float* ki = (const float*)d_in[3];
    const float* alpha = (const float*)d_in[4];
    float* out = (float*)d_out;

    char* ws = (char*)d_ws;
    size_t OFFT_BYTES = (size_t)B * COUT * L * 4;
    size_t TBL_BYTES = (size_t)65 * 4096 * 4;
    unsigned* outfft_d = (unsigned*)ws;
    float* Pmag = (float*)(ws + OFFT_BYTES);
    float* Pph  = (float*)(ws + OFFT_BYTES + TBL_BYTES);
    float* pmin = (float*)(ws + OFFT_BYTES + 2 * TBL_BYTES);
    float* pmax = pmin + 1024;
    float* mmin = pmax + 1024;
    float* mmax = mmin + 16;

    unsigned* Xd = (unsigned*)d_out;   // p-blocked pair-dword x_fft; overwritten by k_ifft

    hipLaunchKernelGGL(k_reduce1, dim3(1024), dim3(256), 0, stream, xr, xi, pmin, pmax);
    hipLaunchKernelGGL(k_reduce2, dim3(16), dim3(64), 0, stream, pmin, pmax, mmin, mmax);
    hipLaunchKernelGGL(k_kstats, dim3(4096), dim3(64), 0, stream, kr, ki, Pmag, Pph);
    hipLaunchKernelGGL(k_fwd, dim3(1024), dim3(512), 0, stream, xr, xi, mmin, mmax, Xd);
    hipLaunchKernelGGL(k_gemm, dim3(1024), dim3(256), 0, stream, Xd, Pmag, Pph, outfft_d);
    hipLaunchKernelGGL(k_ifft, dim3(1024), dim3(512), 0, stream,
                       (const __hip_bfloat162*)outfft_d, alpha, out);
}

// Round 16
// 136.236 us; speedup vs baseline: 1.5367x; 1.2815x over previous
//
#include <hip/hip_runtime.h>
#include <hip/hip_fp16.h>
#include <hip/hip_bf16.h>
#include <math.h>

#define L 8192
#define LOG2L 13
#define B 16
#define CIN 64
#define COUT 64
#define KK 64

#define PI_F 3.14159265358979323846f

typedef float f4v __attribute__((ext_vector_type(4)));
typedef short s8v __attribute__((ext_vector_type(8)));

// scatter swizzle for the bit-reversal permute
__device__ __forceinline__ int swz(int n) { return n ^ ((n >> 8) & 31); }
// butterfly-storage swizzle (radix-16 passes conflict-free)
__device__ __forceinline__ int PHI(int n) { return n ^ ((((n >> 5) ^ (n >> 9)) & 15) << 1); }

// native sincos (revolutions + fract range reduction)
__device__ __forceinline__ void nsincos(float ang, float* sn, float* cs) {
    float r = ang * 0.15915494309189535f;
    r = r - floorf(r);
    *sn = __builtin_amdgcn_sinf(r);
    *cs = __builtin_amdgcn_cosf(r);
}

// f32 -> bf16 bits, round-to-nearest-even
__device__ __forceinline__ unsigned short f2bf(float f) {
    unsigned u = __builtin_bit_cast(unsigned, f);
    u += 0x7FFFu + ((u >> 16) & 1u);
    return (unsigned short)(u >> 16);
}
// pack two f32 -> bf16x2 dword (round-half-up)
__device__ __forceinline__ unsigned pkbf(float a, float b) {
    unsigned ua = __builtin_bit_cast(unsigned, a) + 0x8000u;
    unsigned ub = __builtin_bit_cast(unsigned, b) + 0x8000u;
    return (ub & 0xFFFF0000u) | (ua >> 16);
}

// fused radix-4 butterfly (two radix-2 stages)
template<int INV>
__device__ __forceinline__ void bfly4(float& u0r, float& u0i, float& u1r, float& u1i,
                                      float& v0r, float& v0i, float& v1r, float& v1i,
                                      float w1r, float w1i, float w2r, float w2i) {
    float A0r = u0r + v0r, A0i = u0i + v0i;
    float t0r = u0r - v0r, t0i = u0i - v0i;
    float B0r = t0r * w1r - t0i * w1i, B0i = t0r * w1i + t0i * w1r;
    float A1r = u1r + v1r, A1i = u1i + v1i;
    float t1r = u1r - v1r, t1i = u1i - v1i;
    float wr = t1r * w1r - t1i * w1i, wi = t1r * w1i + t1i * w1r;
    float B1r = INV ? -wi : wi;
    float B1i = INV ? wr : -wr;
    u0r = A0r + A1r; u0i = A0i + A1i;
    float d0r = A0r - A1r, d0i = A0i - A1i;
    u1r = d0r * w2r - d0i * w2i; u1i = d0r * w2i + d0i * w2r;
    v0r = B0r + B1r; v0i = B0i + B1i;
    float d1r = B0r - B1r, d1i = B0i - B1i;
    v1r = d1r * w2r - d1i * w2i; v1i = d1r * w2i + d1i * w2r;
}

// radix-16 on 16 register points; (wc,ws) = e^{∓i pi j1/(8 len2)}
template<int INV>
__device__ __forceinline__ void radix16(float* xr, float* xi, float wc, float ws) {
    const float C8 = 0.9238795325112867f, S8 = 0.3826834323650898f, C4 = 0.7071067811865476f;
    float e1r = C8, e1i = INV ? S8 : -S8;
    float e2r = C4, e2i = INV ? C4 : -C4;
    float e3r = S8, e3i = INV ? C8 : -C8;
    float a1r[4], a1i[4], a2r[4], a2i[4];
    a1r[0] = wc;                    a1i[0] = ws;
    a1r[1] = wc * e1r - ws * e1i;   a1i[1] = wc * e1i + ws * e1r;
    a1r[2] = wc * e2r - ws * e2i;   a1i[2] = wc * e2i + ws * e2r;
    a1r[3] = wc * e3r - ws * e3i;   a1i[3] = wc * e3i + ws * e3r;
#pragma unroll
    for (int q = 0; q < 4; ++q) {
        a2r[q] = a1r[q] * a1r[q] - a1i[q] * a1i[q];
        a2i[q] = 2.f * a1r[q] * a1i[q];
    }
    float b1r = a2r[0] * a2r[0] - a2i[0] * a2i[0], b1i = 2.f * a2r[0] * a2i[0];
    float b2r = b1r * b1r - b1i * b1i, b2i = 2.f * b1r * b1i;
#pragma unroll
    for (int q = 0; q < 4; ++q)
        bfly4<INV>(xr[q], xi[q], xr[q + 4], xi[q + 4], xr[q + 8], xi[q + 8],
                   xr[q + 12], xi[q + 12], a1r[q], a1i[q], a2r[q], a2i[q]);
#pragma unroll
    for (int c = 0; c < 4; ++c)
        bfly4<INV>(xr[4 * c], xi[4 * c], xr[4 * c + 1], xi[4 * c + 1],
                   xr[4 * c + 2], xi[4 * c + 2], xr[4 * c + 3], xi[4 * c + 3],
                   b1r, b1i, b2r, b2i);
}

// ---------------- kernel 1: partial per-batch min/max of |x| ----------------
__global__ __launch_bounds__(256) void k_reduce1(const float* __restrict__ xr,
                                                 const float* __restrict__ xi,
                                                 float* __restrict__ pmin,
                                                 float* __restrict__ pmax) {
    int bid = blockIdx.x;
    int batch = bid >> 6, slice = bid & 63;
    size_t base = (size_t)batch * CIN * L + (size_t)slice * L;
    int tid = threadIdx.x;
    float mn = 3.4e38f, mx = 0.0f;
    for (int r = 0; r < 32; ++r) {
        int idx = r * 256 + tid;
        float a = xr[base + idx], b = xi[base + idx];
        float m = sqrtf(a * a + b * b);
        mn = fminf(mn, m);
        mx = fmaxf(mx, m);
    }
    __shared__ float smn[4], smx[4];
    for (int off = 32; off >= 1; off >>= 1) {
        mn = fminf(mn, __shfl_down(mn, off));
        mx = fmaxf(mx, __shfl_down(mx, off));
    }
    int wave = tid >> 6;
    if ((tid & 63) == 0) { smn[wave] = mn; smx[wave] = mx; }
    __syncthreads();
    if (tid == 0) {
        for (int w = 1; w < 4; ++w) { mn = fminf(mn, smn[w]); mx = fmaxf(mx, smx[w]); }
        pmin[bid] = mn;
        pmax[bid] = mx;
    }
}

// ---------------- kernel 2: final min/max ----------------
__global__ __launch_bounds__(64) void k_reduce2(const float* __restrict__ pmin,
                                                const float* __restrict__ pmax,
                                                float* __restrict__ mmin,
                                                float* __restrict__ mmax) {
    int b = blockIdx.x, t = threadIdx.x;
    float mn = pmin[b * 64 + t], mx = pmax[b * 64 + t];
    for (int off = 32; off >= 1; off >>= 1) {
        mn = fminf(mn, __shfl_down(mn, off));
        mx = fmaxf(mx, __shfl_down(mx, off));
    }
    if (t == 0) { mmin[b] = mn; mmax[b] = mx; }
}

// ---------------- kernel 3: kernel FFT stats, B-FRAGMENT-PACKED tables ----------------
__global__ __launch_bounds__(64) void k_kstats(const float* __restrict__ kr,
                                               const float* __restrict__ ki,
                                               float* __restrict__ Pmag,
                                               float* __restrict__ Pph) {
    int row = blockIdx.x;   // io*64 + jn
    int k = threadIdx.x;
    __shared__ float sr[64], si[64];
    sr[k] = kr[row * 64 + k];
    si[k] = ki[row * 64 + k];
    __syncthreads();
    float ar = 0.f, ai = 0.f;
    for (int n = 0; n < 64; ++n) {
        int m = (n * k) & 63;
        float ang = -2.0f * PI_F * (float)m * (1.0f / 64.0f);
        float s, c;
        __sincosf(ang, &s, &c);
        ar += sr[n] * c - si[n] * s;
        ai += sr[n] * s + si[n] * c;
    }
    float mag = sqrtf(ar * ar + ai * ai);
    float ph = atan2f(ai, ar);
    int io = row >> 6, jn = row & 63;
    int ic = io >> 4, l15 = io & 15;
    int jc = jn >> 5, hi = (jn >> 3) & 3, e = jn & 7;
    int lane = hi * 16 + l15;
    size_t off = (size_t)k * 4096 + (ic * 2 + jc) * 512 + lane * 8 + e;
    Pmag[off] = mag;
    Pph[off] = ph;
    if (k == 63) {
        Pmag[off + 4096] = mag;
        Pph[off + 4096] = ph;
    }
}

// ---------------- kernel 4: coupling + stage0-in-regs + 3 radix-16 passes + permute ----------------
// x_fft written as interleaved bf16-pair dwords in p-blocked layout:
// X[pblk=512][row=1024][16 p], dword = R | I<<16, natural-order p = pblk*16+pi.
__global__ __launch_bounds__(512) void k_fwd(const float* __restrict__ xr,
                                             const float* __restrict__ xi,
                                             const float* __restrict__ mmin_,
                                             const float* __restrict__ mmax_,
                                             unsigned* __restrict__ Xd) {
    __shared__ float sRe[L];
    __shared__ float sIm[L];
    int row = blockIdx.x;          // b*64 + j
    int b = row >> 6;
    int tid = threadIdx.x;
    float mmin = mmin_[b], mmax = mmax_[b];
    float span = mmax - mmin;
    float invden = 1.0f / (span + 1e-10f);
    size_t base = (size_t)row * L;

    float vr[16], vi[16];
#pragma unroll
    for (int r = 0; r < 16; ++r) {
        int idx = r * 512 + tid;
        float a = xr[base + idx], c = xi[base + idx];
        float m = sqrtf(a * a + c * c);
        float xn = (m - mmin) * invden;
#pragma unroll
        for (int it = 0; it < 5; ++it) xn = 3.8f * xn * (1.0f - xn);
        float mc = xn * span + mmin;
        float scale = (m > 0.0f) ? (mc / m) : 0.0f;
        vr[r] = a * scale;
        vi[r] = c * scale;
    }
    // stage 0 (len 4096) in registers
#pragma unroll
    for (int r = 0; r < 8; ++r) {
        float sn, cs;
        nsincos(-PI_F * (float)(r * 512 + tid) * (1.0f / 4096.0f), &sn, &cs);
        float ar = vr[r], ai = vi[r], br = vr[r + 8], bi = vi[r + 8];
        vr[r] = ar + br; vi[r] = ai + bi;
        float dr = ar - br, di = ai - bi;
        vr[r + 8] = dr * cs - di * sn;
        vi[r + 8] = dr * sn + di * cs;
    }
#pragma unroll
    for (int r = 0; r < 16; ++r) {
        int a = PHI(r * 512 + tid);
        sRe[a] = vr[r]; sIm[a] = vi[r];
    }
    __syncthreads();

    // pass A: stages 1-4, len2=256
    {
        int j1 = tid & 255, bA = (tid >> 8) << 12;
#pragma unroll
        for (int m = 0; m < 16; ++m) {
            int a = PHI(bA + j1 + (m << 8));
            vr[m] = sRe[a]; vi[m] = sIm[a];
        }
        float sn, cs;
        nsincos(-PI_F * (float)j1 * (1.0f / 2048.0f), &sn, &cs);
        radix16<0>(vr, vi, cs, sn);
#pragma unroll
        for (int m = 0; m < 16; ++m) {
            int a = PHI(bA + j1 + (m << 8));
            sRe[a] = vr[m]; sIm[a] = vi[m];
        }
    }
    __syncthreads();
    // pass B: stages 5-8, len2=16
    {
        int j1 = tid & 15, bB = (tid >> 4) << 8;
#pragma unroll
        for (int m = 0; m < 16; ++m) {
            int a = PHI(bB + j1 + (m << 4));
            vr[m] = sRe[a]; vi[m] = sIm[a];
        }
        float sn, cs;
        nsincos(-PI_F * (float)j1 * (1.0f / 128.0f), &sn, &cs);
        radix16<0>(vr, vi, cs, sn);
#pragma unroll
        for (int m = 0; m < 16; ++m) {
            int a = PHI(bB + j1 + (m << 4));
            sRe[a] = vr[m]; sIm[a] = vi[m];
        }
    }
    __syncthreads();
    // pass C: stages 9-12, len2=1
    {
        float2* f2R = (float2*)sRe;
        float2* f2I = (float2*)sIm;
#pragma unroll
        for (int m = 0; m < 8; ++m) {
            int a = PHI(tid * 16 + 2 * m) >> 1;
            float2 vR = f2R[a], vI = f2I[a];
            vr[2 * m] = vR.x; vr[2 * m + 1] = vR.y;
            vi[2 * m] = vI.x; vi[2 * m + 1] = vI.y;
        }
        radix16<0>(vr, vi, 1.0f, 0.0f);
#pragma unroll
        for (int m = 0; m < 8; ++m) {
            int a = PHI(tid * 16 + 2 * m) >> 1;
            f2R[a] = make_float2(vr[2 * m], vr[2 * m + 1]);
            f2I[a] = make_float2(vi[2 * m], vi[2 * m + 1]);
        }
    }
    __syncthreads();

    // bitrev permute: read linear (PHI layout) -> scatter to swz layout
#pragma unroll
    for (int r = 0; r < 16; ++r) {
        int a = PHI(r * 512 + tid);
        vr[r] = sRe[a]; vi[r] = sIm[a];
    }
    __syncthreads();
#pragma unroll
    for (int r = 0; r < 16; ++r) {
        int idx = r * 512 + tid;
        int n = (int)(__brev((unsigned)idx) >> 19);
        int a = swz(n);
        sRe[a] = vr[r]; sIm[a] = vi[r];
    }
    __syncthreads();

    // pack (R,I) per p, write this thread's 16-p block (64B full line per row)
    {
        unsigned o16[16];
        int mask = (tid >> 4) & 31;
#pragma unroll
        for (int pi = 0; pi < 16; ++pi) {
            int a = (tid * 16 + pi) ^ mask;   // == swz(tid*16+pi)
            o16[pi] = ((unsigned)f2bf(sIm[a]) << 16) | f2bf(sRe[a]);
        }
        size_t ob = (size_t)tid * 16384 + (size_t)row * 16;
#pragma unroll
        for (int k = 0; k < 4; ++k)
            *(uint4*)&Xd[ob + 4 * k] = make_uint4(o16[4 * k], o16[4 * k + 1],
                                                  o16[4 * k + 2], o16[4 * k + 3]);
    }
}

// ---------------- kernel 5: MFMA complex GEMM over frequencies ----------------
// Block = one 8-p window, 256 threads (4 waves x 2 p). Dense coalesced X reads;
// (R,I) de-interleaved DURING STAGING into r12's planar LDS layout, so the MAC
// phase keeps r12's proven register profile (tables loaded once per (jc,ic),
// shared by both q; s8v frag loads; accR[2][4] live).
#define PBG 8
#define REG 4624   // bytes per p-region: 2 planes x (16 rows x 144B), 16-aligned
__global__ __launch_bounds__(256) void k_gemm(const unsigned* __restrict__ X,
                                              const float* __restrict__ Pmag,
                                              const float* __restrict__ Pph,
                                              unsigned* __restrict__ outd) {
    __shared__ uint4 ldsbuf[(PBG * REG) / 16];   // 36,992 B
    char* lds = (char*)ldsbuf;
    int tid = threadIdx.x;
    int bid = blockIdx.x;   // 1024
    int pwin = ((bid & 7) << 7) + (bid >> 3);   // XCD-contiguous; half-siblings adjacent
    int p0 = pwin * PBG;
    int half = pwin & 1;
    const unsigned* src = X + (size_t)(pwin >> 1) * 16384 + half * 8;

    // stage: dense reads (2 x 16B per 64B row-chunk), de-interleave to planar
#pragma unroll
    for (int k = 0; k < 8; ++k) {
        int u = k * 256 + tid;              // 0..2047
        int row = u >> 1;                   // b*64 + j
        int g = u & 1;
        uint4 v = *(const uint4*)&src[(size_t)row * 16 + g * 4];
        int base = (row >> 6) * 144 + (row & 63) * 2;
        unsigned dw[4] = {v.x, v.y, v.z, v.w};
#pragma unroll
        for (int c = 0; c < 4; ++c) {
            int pl = g * 4 + c;
            *(unsigned short*)&lds[pl * REG + base] = (unsigned short)(dw[c] & 0xFFFFu);
            *(unsigned short*)&lds[pl * REG + 2304 + base] = (unsigned short)(dw[c] >> 16);
        }
    }
    __syncthreads();

    int lane = tid & 63, wid = tid >> 6;
    int l15 = lane & 15, l4 = lane >> 4;

    // this wave's p-pair (share i0k; w differs)
    int pA = p0 + wid * 2;
    float posA = ((float)pA + 0.5f) * (1.0f / 128.0f) - 0.5f;
    posA = fmaxf(posA, 0.0f);
    int i0k = (int)posA;
    bool clampv = (i0k >= KK - 1);
    float wq[2];
#pragma unroll
    for (int q = 0; q < 2; ++q) {
        float pos = ((float)(pA + q) + 0.5f) * (1.0f / 128.0f) - 0.5f;
        pos = fmaxf(pos, 0.0f);
        wq[q] = clampv ? 0.0f : (pos - (float)i0k);
    }
    const float* mb0 = Pmag + (size_t)i0k * 4096;
    const float* pb0 = Pph + (size_t)i0k * 4096;

    f4v accR[2][4], accI[2][4];
#pragma unroll
    for (int q = 0; q < 2; ++q)
#pragma unroll
        for (int ic = 0; ic < 4; ++ic) { accR[q][ic] = (f4v)0.0f; accI[q][ic] = (f4v)0.0f; }

#pragma unroll
    for (int jc = 0; jc < 2; ++jc) {
        int jb2 = (jc * 32 + l4 * 8) * 2;    // byte offset of A-frag j-slice
        s8v xR0 = *(const s8v*)&lds[(wid * 2 + 0) * REG + l15 * 144 + jb2];
        s8v xI0 = *(const s8v*)&lds[(wid * 2 + 0) * REG + 2304 + l15 * 144 + jb2];
        s8v xR1 = *(const s8v*)&lds[(wid * 2 + 1) * REG + l15 * 144 + jb2];
        s8v xI1 = *(const s8v*)&lds[(wid * 2 + 1) * REG + 2304 + l15 * 144 + jb2];
#pragma unroll
        for (int ic = 0; ic < 4; ++ic) {
            int tb = (ic * 2 + jc) * 512 + lane * 8;   // coalesced 2KB wave burst
            float4 m0a = *(const float4*)(mb0 + tb);
            float4 m0b = *(const float4*)(mb0 + tb + 4);
            float4 m1a = *(const float4*)(mb0 + 4096 + tb);
            float4 m1b = *(const float4*)(mb0 + 4096 + tb + 4);
            float4 q0a = *(const float4*)(pb0 + tb);
            float4 q0b = *(const float4*)(pb0 + tb + 4);
            float4 q1a = *(const float4*)(pb0 + 4096 + tb);
            float4 q1b = *(const float4*)(pb0 + 4096 + tb + 4);
            float m0v[8] = {m0a.x, m0a.y, m0a.z, m0a.w, m0b.x, m0b.y, m0b.z, m0b.w};
            float m1v[8] = {m1a.x, m1a.y, m1a.z, m1a.w, m1b.x, m1b.y, m1b.z, m1b.w};
            float q0v[8] = {q0a.x, q0a.y, q0a.z, q0a.w, q0b.x, q0b.y, q0b.z, q0b.w};
            float q1v[8] = {q1a.x, q1a.y, q1a.z, q1a.w, q1b.x, q1b.y, q1b.z, q1b.w};
#pragma unroll
            for (int q = 0; q < 2; ++q) {
                float w = wq[q];
                float kr[8], ki[8];
#pragma unroll
                for (int e = 0; e < 8; ++e) {
                    float mm = m0v[e] + (m1v[e] - m0v[e]) * w;
                    float ph = q0v[e] + (q1v[e] - q0v[e]) * w;
                    float sn, cs;
                    nsincos(ph, &sn, &cs);
                    kr[e] = mm * cs;
                    ki[e] = mm * sn;
                }
                union { unsigned u[4]; s8v v; } kR, kIp, kIn;
#pragma unroll
                for (int t = 0; t < 4; ++t) {
                    kR.u[t] = pkbf(kr[2 * t], kr[2 * t + 1]);
                    kIp.u[t] = pkbf(ki[2 * t], ki[2 * t + 1]);
                    kIn.u[t] = kIp.u[t] ^ 0x80008000u;
                }
                s8v xR = q ? xR1 : xR0;
                s8v xI = q ? xI1 : xI0;
                accR[q][ic] = __builtin_amdgcn_mfma_f32_16x16x32_bf16(xR, kR.v, accR[q][ic], 0, 0, 0);
                accR[q][ic] = __builtin_amdgcn_mfma_f32_16x16x32_bf16(xI, kIn.v, accR[q][ic], 0, 0, 0);
                accI[q][ic] = __builtin_amdgcn_mfma_f32_16x16x32_bf16(xR, kIp.v, accI[q][ic], 0, 0, 0);
                accI[q][ic] = __builtin_amdgcn_mfma_f32_16x16x32_bf16(xI, kR.v, accI[q][ic], 0, 0, 0);
            }
        }
    }

    // overlay: out[b*64+i] bf16x2 into this wave's (now dead) x regions
#pragma unroll
    for (int q = 0; q < 2; ++q) {
        int pp = wid * 2 + q;
#pragma unroll
        for (int ic = 0; ic < 4; ++ic)
#pragma unroll
            for (int e = 0; e < 4; ++e) {
                int ro = (l4 * 4 + e) * 64 + ic * 16 + l15;   // b*64 + i
                unsigned val = ((unsigned)f2bf(accI[q][ic][e]) << 16) | f2bf(accR[q][ic][e]);
                *(unsigned*)&lds[pp * REG + ro * 4] = val;
            }
    }
    __syncthreads();

    // store: 8 lanes x 8 consecutive dwords per row group (proven, no RMW amp)
#pragma unroll
    for (int k = 0; k < 32; ++k) {
        int row = k * 32 + (tid >> 3);
        unsigned v = *(const unsigned*)&lds[(tid & 7) * REG + row * 4];
        outd[(size_t)row * 8192 + p0 + (tid & 7)] = v;
    }
}

// ---------------- kernel 6: inverse FFT (stage0-in-regs + 3 radix-16) + activation ----------------
__global__ __launch_bounds__(512) void k_ifft(const __hip_bfloat162* __restrict__ outfft,
                                              const float* __restrict__ alpha_,
                                              float* __restrict__ out) {
    __shared__ float sRe[L];
    __shared__ float sIm[L];
    int row = blockIdx.x;          // b*64 + i
    int tid = threadIdx.x;
    float alpha = alpha_[0];
    size_t base = (size_t)row * L;

    float vr[16], vi[16];
#pragma unroll
    for (int r = 0; r < 16; ++r) {
        __hip_bfloat162 v = outfft[base + r * 512 + tid];
        vr[r] = __bfloat162float(v.x);
        vi[r] = __bfloat162float(v.y);
    }
#pragma unroll
    for (int r = 0; r < 8; ++r) {
        float sn, cs;
        nsincos(PI_F * (float)(r * 512 + tid) * (1.0f / 4096.0f), &sn, &cs);
        float ar = vr[r], ai = vi[r], br = vr[r + 8], bi = vi[r + 8];
        vr[r] = ar + br; vi[r] = ai + bi;
        float dr = ar - br, di = ai - bi;
        vr[r + 8] = dr * cs - di * sn;
        vi[r + 8] = dr * sn + di * cs;
    }
#pragma unroll
    for (int r = 0; r < 16; ++r) {
        int a = PHI(r * 512 + tid);
        sRe[a] = vr[r]; sIm[a] = vi[r];
    }
    __syncthreads();

    // pass A
    {
        int j1 = tid & 255, bA = (tid >> 8) << 12;
#pragma unroll
        for (int m = 0; m < 16; ++m) {
            int a = PHI(bA + j1 + (m << 8));
            vr[m] = sRe[a]; vi[m] = sIm[a];
        }
        float sn, cs;
        nsincos(PI_F * (float)j1 * (1.0f / 2048.0f), &sn, &cs);
        radix16<1>(vr, vi, cs, sn);
#pragma unroll
        for (int m = 0; m < 16; ++m) {
            int a = PHI(bA + j1 + (m << 8));
            sRe[a] = vr[m]; sIm[a] = vi[m];
        }
    }
    __syncthreads();
    // pass B
    {
        int j1 = tid & 15, bB = (tid >> 4) << 8;
#pragma unroll
        for (int m = 0; m < 16; ++m) {
            int a = PHI(bB + j1 + (m << 4));
            vr[m] = sRe[a]; vi[m] = sIm[a];
        }
        float sn, cs;
        nsincos(PI_F * (float)j1 * (1.0f / 128.0f), &sn, &cs);
        radix16<1>(vr, vi, cs, sn);
#pragma unroll
        for (int m = 0; m < 16; ++m) {
            int a = PHI(bB + j1 + (m << 4));
            sRe[a] = vr[m]; sIm[a] = vi[m];
        }
    }
    __syncthreads();
    // pass C
    {
        float2* f2R = (float2*)sRe;
        float2* f2I = (float2*)sIm;
#pragma unroll
        for (int m = 0; m < 8; ++m) {
            int a = PHI(tid * 16 + 2 * m) >> 1;
            float2 vR = f2R[a], vI = f2I[a];
            vr[2 * m] = vR.x; vr[2 * m + 1] = vR.y;
            vi[2 * m] = vI.x; vi[2 * m + 1] = vI.y;
        }
        radix16<1>(vr, vi, 1.0f, 0.0f);
#pragma unroll
        for (int m = 0; m < 8; ++m) {
            int a = PHI(tid * 16 + 2 * m) >> 1;
            f2R[a] = make_float2(vr[2 * m], vr[2 * m + 1]);
            f2I[a] = make_float2(vi[2 * m], vi[2 * m + 1]);
        }
    }
    __syncthreads();

#pragma unroll
    for (int r = 0; r < 16; ++r) {
        int a = PHI(r * 512 + tid);
        vr[r] = sRe[a]; vi[r] = sIm[a];
    }
    __syncthreads();
#pragma unroll
    for (int r = 0; r < 16; ++r) {
        int idx = r * 512 + tid;
        int n = (int)(__brev((unsigned)idx) >> 19);
        int a = swz(n);
        sRe[a] = vr[r]; sIm[a] = vi[r];
    }
    __syncthreads();

    const float invN = 1.0f / (float)L;
#pragma unroll
    for (int rpt = 0; rpt < L / 512; ++rpt) {
        int n = rpt * 512 + tid;
        float act = sinf(alpha * (float)n);
        out[base + n] = sRe[swz(n)] * act * invN;
    }
}

// ---------------- launch ----------------
extern "C" void kernel_launch(void* const* d_in, const int* in_sizes, int n_in,
                              void* d_out, int out_size, void* d_ws, size_t ws_size,
                              hipStream_t stream) {
    const float* xr = (const float*)d_in[0];
    const float* xi = (const float*)d_in[1];
    const float* kr = (const float*)d_in[2];
    const float* ki = (const float*)d_in[3];
    const float* alpha = (const float*)d_in[4];
    float* out = (float*)d_out;

    char* ws = (char*)d_ws;
    size_t OFFT_BYTES = (size_t)B * COUT * L * 4;
    size_t TBL_BYTES = (size_t)65 * 4096 * 4;
    unsigned* outfft_d = (unsigned*)ws;
    float* Pmag = (float*)(ws + OFFT_BYTES);
    float* Pph  = (float*)(ws + OFFT_BYTES + TBL_BYTES);
    float* pmin = (float*)(ws + OFFT_BYTES + 2 * TBL_BYTES);
    float* pmax = pmin + 1024;
    float* mmin = pmax + 1024;
    float* mmax = mmin + 16;

    unsigned* Xd = (unsigned*)d_out;   // p-blocked pair-dword x_fft; overwritten by k_ifft

    hipLaunchKernelGGL(k_reduce1, dim3(1024), dim3(256), 0, stream, xr, xi, pmin, pmax);
    hipLaunchKernelGGL(k_reduce2, dim3(16), dim3(64), 0, stream, pmin, pmax, mmin, mmax);
    hipLaunchKernelGGL(k_kstats, dim3(4096), dim3(64), 0, stream, kr, ki, Pmag, Pph);
    hipLaunchKernelGGL(k_fwd, dim3(1024), dim3(512), 0, stream, xr, xi, mmin, mmax, Xd);
    hipLaunchKernelGGL(k_gemm, dim3(1024), dim3(256), 0, stream, Xd, Pmag, Pph, outfft_d);
    hipLaunchKernelGGL(k_ifft, dim3(1024), dim3(512), 0, stream,
                       (const __hip_bfloat162*)outfft_d, alpha, out);
}

// Round 17
// 130.898 us; speedup vs baseline: 1.5993x; 1.0408x over previous
//
#include <hip/hip_runtime.h>
#include <hip/hip_fp16.h>
#include <hip/hip_bf16.h>
#include <math.h>

#define L 8192
#define LOG2L 13
#define B 16
#define CIN 64
#define COUT 64
#define KK 64

#define PI_F 3.14159265358979323846f

typedef float f4v __attribute__((ext_vector_type(4)));
typedef short s8v __attribute__((ext_vector_type(8)));

// butterfly-storage swizzle (radix-16 passes conflict-free; gather ~4-way)
__device__ __forceinline__ int PHI(int n) { return n ^ ((((n >> 5) ^ (n >> 9)) & 15) << 1); }

// native sincos (revolutions + fract range reduction)
__device__ __forceinline__ void nsincos(float ang, float* sn, float* cs) {
    float r = ang * 0.15915494309189535f;
    r = r - floorf(r);
    *sn = __builtin_amdgcn_sinf(r);
    *cs = __builtin_amdgcn_cosf(r);
}

// f32 -> bf16 bits, round-to-nearest-even
__device__ __forceinline__ unsigned short f2bf(float f) {
    unsigned u = __builtin_bit_cast(unsigned, f);
    u += 0x7FFFu + ((u >> 16) & 1u);
    return (unsigned short)(u >> 16);
}
// pack two f32 -> bf16x2 dword (round-half-up)
__device__ __forceinline__ unsigned pkbf(float a, float b) {
    unsigned ua = __builtin_bit_cast(unsigned, a) + 0x8000u;
    unsigned ub = __builtin_bit_cast(unsigned, b) + 0x8000u;
    return (ub & 0xFFFF0000u) | (ua >> 16);
}

// fused radix-4 butterfly (two radix-2 stages)
template<int INV>
__device__ __forceinline__ void bfly4(float& u0r, float& u0i, float& u1r, float& u1i,
                                      float& v0r, float& v0i, float& v1r, float& v1i,
                                      float w1r, float w1i, float w2r, float w2i) {
    float A0r = u0r + v0r, A0i = u0i + v0i;
    float t0r = u0r - v0r, t0i = u0i - v0i;
    float B0r = t0r * w1r - t0i * w1i, B0i = t0r * w1i + t0i * w1r;
    float A1r = u1r + v1r, A1i = u1i + v1i;
    float t1r = u1r - v1r, t1i = u1i - v1i;
    float wr = t1r * w1r - t1i * w1i, wi = t1r * w1i + t1i * w1r;
    float B1r = INV ? -wi : wi;
    float B1i = INV ? wr : -wr;
    u0r = A0r + A1r; u0i = A0i + A1i;
    float d0r = A0r - A1r, d0i = A0i - A1i;
    u1r = d0r * w2r - d0i * w2i; u1i = d0r * w2i + d0i * w2r;
    v0r = B0r + B1r; v0i = B0i + B1i;
    float d1r = B0r - B1r, d1i = B0i - B1i;
    v1r = d1r * w2r - d1i * w2i; v1i = d1r * w2i + d1i * w2r;
}

// radix-16 on 16 register points; (wc,ws) = e^{∓i pi j1/(8 len2)}
template<int INV>
__device__ __forceinline__ void radix16(float* xr, float* xi, float wc, float ws) {
    const float C8 = 0.9238795325112867f, S8 = 0.3826834323650898f, C4 = 0.7071067811865476f;
    float e1r = C8, e1i = INV ? S8 : -S8;
    float e2r = C4, e2i = INV ? C4 : -C4;
    float e3r = S8, e3i = INV ? C8 : -C8;
    float a1r[4], a1i[4], a2r[4], a2i[4];
    a1r[0] = wc;                    a1i[0] = ws;
    a1r[1] = wc * e1r - ws * e1i;   a1i[1] = wc * e1i + ws * e1r;
    a1r[2] = wc * e2r - ws * e2i;   a1i[2] = wc * e2i + ws * e2r;
    a1r[3] = wc * e3r - ws * e3i;   a1i[3] = wc * e3i + ws * e3r;
#pragma unroll
    for (int q = 0; q < 4; ++q) {
        a2r[q] = a1r[q] * a1r[q] - a1i[q] * a1i[q];
        a2i[q] = 2.f * a1r[q] * a1i[q];
    }
    float b1r = a2r[0] * a2r[0] - a2i[0] * a2i[0], b1i = 2.f * a2r[0] * a2i[0];
    float b2r = b1r * b1r - b1i * b1i, b2i = 2.f * b1r * b1i;
#pragma unroll
    for (int q = 0; q < 4; ++q)
        bfly4<INV>(xr[q], xi[q], xr[q + 4], xi[q + 4], xr[q + 8], xi[q + 8],
                   xr[q + 12], xi[q + 12], a1r[q], a1i[q], a2r[q], a2i[q]);
#pragma unroll
    for (int c = 0; c < 4; ++c)
        bfly4<INV>(xr[4 * c], xi[4 * c], xr[4 * c + 1], xi[4 * c + 1],
                   xr[4 * c + 2], xi[4 * c + 2], xr[4 * c + 3], xi[4 * c + 3],
                   b1r, b1i, b2r, b2i);
}

// ---------------- kernel 1: partial per-batch min/max of |x| ----------------
__global__ __launch_bounds__(256) void k_reduce1(const float* __restrict__ xr,
                                                 const float* __restrict__ xi,
                                                 float* __restrict__ pmin,
                                                 float* __restrict__ pmax) {
    int bid = blockIdx.x;
    int batch = bid >> 6, slice = bid & 63;
    size_t base = (size_t)batch * CIN * L + (size_t)slice * L;
    int tid = threadIdx.x;
    float mn = 3.4e38f, mx = 0.0f;
    for (int r = 0; r < 32; ++r) {
        int idx = r * 256 + tid;
        float a = xr[base + idx], b = xi[base + idx];
        float m = sqrtf(a * a + b * b);
        mn = fminf(mn, m);
        mx = fmaxf(mx, m);
    }
    __shared__ float smn[4], smx[4];
    for (int off = 32; off >= 1; off >>= 1) {
        mn = fminf(mn, __shfl_down(mn, off));
        mx = fmaxf(mx, __shfl_down(mx, off));
    }
    int wave = tid >> 6;
    if ((tid & 63) == 0) { smn[wave] = mn; smx[wave] = mx; }
    __syncthreads();
    if (tid == 0) {
        for (int w = 1; w < 4; ++w) { mn = fminf(mn, smn[w]); mx = fmaxf(mx, smx[w]); }
        pmin[bid] = mn;
        pmax[bid] = mx;
    }
}

// ---------------- kernel 2: final min/max ----------------
__global__ __launch_bounds__(64) void k_reduce2(const float* __restrict__ pmin,
                                                const float* __restrict__ pmax,
                                                float* __restrict__ mmin,
                                                float* __restrict__ mmax) {
    int b = blockIdx.x, t = threadIdx.x;
    float mn = pmin[b * 64 + t], mx = pmax[b * 64 + t];
    for (int off = 32; off >= 1; off >>= 1) {
        mn = fminf(mn, __shfl_down(mn, off));
        mx = fmaxf(mx, __shfl_down(mx, off));
    }
    if (t == 0) { mmin[b] = mn; mmax[b] = mx; }
}

// ---------------- kernel 3: kernel FFT stats, B-FRAGMENT-PACKED tables ----------------
__global__ __launch_bounds__(64) void k_kstats(const float* __restrict__ kr,
                                               const float* __restrict__ ki,
                                               float* __restrict__ Pmag,
                                               float* __restrict__ Pph) {
    int row = blockIdx.x;   // io*64 + jn
    int k = threadIdx.x;
    __shared__ float sr[64], si[64];
    sr[k] = kr[row * 64 + k];
    si[k] = ki[row * 64 + k];
    __syncthreads();
    float ar = 0.f, ai = 0.f;
    for (int n = 0; n < 64; ++n) {
        int m = (n * k) & 63;
        float ang = -2.0f * PI_F * (float)m * (1.0f / 64.0f);
        float s, c;
        __sincosf(ang, &s, &c);
        ar += sr[n] * c - si[n] * s;
        ai += sr[n] * s + si[n] * c;
    }
    float mag = sqrtf(ar * ar + ai * ai);
    float ph = atan2f(ai, ar);
    int io = row >> 6, jn = row & 63;
    int ic = io >> 4, l15 = io & 15;
    int jc = jn >> 5, hi = (jn >> 3) & 3, e = jn & 7;
    int lane = hi * 16 + l15;
    size_t off = (size_t)k * 4096 + (ic * 2 + jc) * 512 + lane * 8 + e;
    Pmag[off] = mag;
    Pph[off] = ph;
    if (k == 63) {
        Pmag[off + 4096] = mag;
        Pph[off + 4096] = ph;
    }
}

// ---------------- kernel 4: coupling + stage0-in-regs + 3 radix-16 passes + direct pack ----------------
// x_fft written as interleaved bf16-pair dwords in p-blocked layout:
// X[pblk=512][row=1024][16 p], dword = R | I<<16, natural-order p = pblk*16+pi.
// After pass C, thread tid gathers idx = r*512 + rev9(tid) -> holds freq block
// tid*16 + rev4(r) entirely in registers (no bitrev scatter / re-read needed).
__global__ __launch_bounds__(512) void k_fwd(const float* __restrict__ xr,
                                             const float* __restrict__ xi,
                                             const float* __restrict__ mmin_,
                                             const float* __restrict__ mmax_,
                                             unsigned* __restrict__ Xd) {
    __shared__ float sRe[L];
    __shared__ float sIm[L];
    int row = blockIdx.x;          // b*64 + j
    int b = row >> 6;
    int tid = threadIdx.x;
    float mmin = mmin_[b], mmax = mmax_[b];
    float span = mmax - mmin;
    float invden = 1.0f / (span + 1e-10f);
    size_t base = (size_t)row * L;

    float vr[16], vi[16];
#pragma unroll
    for (int r = 0; r < 16; ++r) {
        int idx = r * 512 + tid;
        float a = xr[base + idx], c = xi[base + idx];
        float m = sqrtf(a * a + c * c);
        float xn = (m - mmin) * invden;
#pragma unroll
        for (int it = 0; it < 5; ++it) xn = 3.8f * xn * (1.0f - xn);
        float mc = xn * span + mmin;
        float scale = (m > 0.0f) ? (mc / m) : 0.0f;
        vr[r] = a * scale;
        vi[r] = c * scale;
    }
    // stage 0 (len 4096) in registers
#pragma unroll
    for (int r = 0; r < 8; ++r) {
        float sn, cs;
        nsincos(-PI_F * (float)(r * 512 + tid) * (1.0f / 4096.0f), &sn, &cs);
        float ar = vr[r], ai = vi[r], br = vr[r + 8], bi = vi[r + 8];
        vr[r] = ar + br; vi[r] = ai + bi;
        float dr = ar - br, di = ai - bi;
        vr[r + 8] = dr * cs - di * sn;
        vi[r + 8] = dr * sn + di * cs;
    }
#pragma unroll
    for (int r = 0; r < 16; ++r) {
        int a = PHI(r * 512 + tid);
        sRe[a] = vr[r]; sIm[a] = vi[r];
    }
    __syncthreads();

    // pass A: stages 1-4, len2=256
    {
        int j1 = tid & 255, bA = (tid >> 8) << 12;
#pragma unroll
        for (int m = 0; m < 16; ++m) {
            int a = PHI(bA + j1 + (m << 8));
            vr[m] = sRe[a]; vi[m] = sIm[a];
        }
        float sn, cs;
        nsincos(-PI_F * (float)j1 * (1.0f / 2048.0f), &sn, &cs);
        radix16<0>(vr, vi, cs, sn);
#pragma unroll
        for (int m = 0; m < 16; ++m) {
            int a = PHI(bA + j1 + (m << 8));
            sRe[a] = vr[m]; sIm[a] = vi[m];
        }
    }
    __syncthreads();
    // pass B: stages 5-8, len2=16
    {
        int j1 = tid & 15, bB = (tid >> 4) << 8;
#pragma unroll
        for (int m = 0; m < 16; ++m) {
            int a = PHI(bB + j1 + (m << 4));
            vr[m] = sRe[a]; vi[m] = sIm[a];
        }
        float sn, cs;
        nsincos(-PI_F * (float)j1 * (1.0f / 128.0f), &sn, &cs);
        radix16<0>(vr, vi, cs, sn);
#pragma unroll
        for (int m = 0; m < 16; ++m) {
            int a = PHI(bB + j1 + (m << 4));
            sRe[a] = vr[m]; sIm[a] = vi[m];
        }
    }
    __syncthreads();
    // pass C: stages 9-12, len2=1
    {
        float2* f2R = (float2*)sRe;
        float2* f2I = (float2*)sIm;
#pragma unroll
        for (int m = 0; m < 8; ++m) {
            int a = PHI(tid * 16 + 2 * m) >> 1;
            float2 vR = f2R[a], vI = f2I[a];
            vr[2 * m] = vR.x; vr[2 * m + 1] = vR.y;
            vi[2 * m] = vI.x; vi[2 * m + 1] = vI.y;
        }
        radix16<0>(vr, vi, 1.0f, 0.0f);
#pragma unroll
        for (int m = 0; m < 8; ++m) {
            int a = PHI(tid * 16 + 2 * m) >> 1;
            f2R[a] = make_float2(vr[2 * m], vr[2 * m + 1]);
            f2I[a] = make_float2(vi[2 * m], vi[2 * m + 1]);
        }
    }
    __syncthreads();

    // direct gather + pack: thread tid owns freq block tid (p = tid*16 + rev4(r))
    {
        int rt = (int)(__brev((unsigned)tid) >> 23);   // rev9(tid)
        unsigned o16[16];
#pragma unroll
        for (int r = 0; r < 16; ++r) {
            int a = PHI(r * 512 + rt);
            int pi = (int)(__brev((unsigned)r) >> 28); // rev4(r)
            o16[pi] = ((unsigned)f2bf(sIm[a]) << 16) | f2bf(sRe[a]);
        }
        size_t ob = (size_t)tid * 16384 + (size_t)row * 16;
#pragma unroll
        for (int k = 0; k < 4; ++k)
            *(uint4*)&Xd[ob + 4 * k] = make_uint4(o16[4 * k], o16[4 * k + 1],
                                                  o16[4 * k + 2], o16[4 * k + 3]);
    }
}

// ---------------- kernel 5: MFMA complex GEMM over frequencies ----------------
// Block = one 8-p window, 256 threads (4 waves x 2 p). Dense coalesced X reads;
// (R,I) de-interleaved DURING STAGING into planar LDS layout; MAC keeps the
// r12-proven register profile.
#define PBG 8
#define REG 4624   // bytes per p-region: 2 planes x (16 rows x 144B), 16-aligned
__global__ __launch_bounds__(256) void k_gemm(const unsigned* __restrict__ X,
                                              const float* __restrict__ Pmag,
                                              const float* __restrict__ Pph,
                                              unsigned* __restrict__ outd) {
    __shared__ uint4 ldsbuf[(PBG * REG) / 16];   // 36,992 B
    char* lds = (char*)ldsbuf;
    int tid = threadIdx.x;
    int bid = blockIdx.x;   // 1024
    int pwin = ((bid & 7) << 7) + (bid >> 3);   // XCD-contiguous; half-siblings adjacent
    int p0 = pwin * PBG;
    int half = pwin & 1;
    const unsigned* src = X + (size_t)(pwin >> 1) * 16384 + half * 8;

    // stage: dense reads (2 x 16B per 64B row-chunk), de-interleave to planar
#pragma unroll
    for (int k = 0; k < 8; ++k) {
        int u = k * 256 + tid;              // 0..2047
        int row = u >> 1;                   // b*64 + j
        int g = u & 1;
        uint4 v = *(const uint4*)&src[(size_t)row * 16 + g * 4];
        int base = (row >> 6) * 144 + (row & 63) * 2;
        unsigned dw[4] = {v.x, v.y, v.z, v.w};
#pragma unroll
        for (int c = 0; c < 4; ++c) {
            int pl = g * 4 + c;
            *(unsigned short*)&lds[pl * REG + base] = (unsigned short)(dw[c] & 0xFFFFu);
            *(unsigned short*)&lds[pl * REG + 2304 + base] = (unsigned short)(dw[c] >> 16);
        }
    }
    __syncthreads();

    int lane = tid & 63, wid = tid >> 6;
    int l15 = lane & 15, l4 = lane >> 4;

    // this wave's p-pair (share i0k; w differs)
    int pA = p0 + wid * 2;
    float posA = ((float)pA + 0.5f) * (1.0f / 128.0f) - 0.5f;
    posA = fmaxf(posA, 0.0f);
    int i0k = (int)posA;
    bool clampv = (i0k >= KK - 1);
    float wq[2];
#pragma unroll
    for (int q = 0; q < 2; ++q) {
        float pos = ((float)(pA + q) + 0.5f) * (1.0f / 128.0f) - 0.5f;
        pos = fmaxf(pos, 0.0f);
        wq[q] = clampv ? 0.0f : (pos - (float)i0k);
    }
    const float* mb0 = Pmag + (size_t)i0k * 4096;
    const float* pb0 = Pph + (size_t)i0k * 4096;

    f4v accR[2][4], accI[2][4];
#pragma unroll
    for (int q = 0; q < 2; ++q)
#pragma unroll
        for (int ic = 0; ic < 4; ++ic) { accR[q][ic] = (f4v)0.0f; accI[q][ic] = (f4v)0.0f; }

#pragma unroll
    for (int jc = 0; jc < 2; ++jc) {
        int jb2 = (jc * 32 + l4 * 8) * 2;    // byte offset of A-frag j-slice
        s8v xR0 = *(const s8v*)&lds[(wid * 2 + 0) * REG + l15 * 144 + jb2];
        s8v xI0 = *(const s8v*)&lds[(wid * 2 + 0) * REG + 2304 + l15 * 144 + jb2];
        s8v xR1 = *(const s8v*)&lds[(wid * 2 + 1) * REG + l15 * 144 + jb2];
        s8v xI1 = *(const s8v*)&lds[(wid * 2 + 1) * REG + 2304 + l15 * 144 + jb2];
#pragma unroll
        for (int ic = 0; ic < 4; ++ic) {
            int tb = (ic * 2 + jc) * 512 + lane * 8;   // coalesced 2KB wave burst
            float4 m0a = *(const float4*)(mb0 + tb);
            float4 m0b = *(const float4*)(mb0 + tb + 4);
            float4 m1a = *(const float4*)(mb0 + 4096 + tb);
            float4 m1b = *(const float4*)(mb0 + 4096 + tb + 4);
            float4 q0a = *(const float4*)(pb0 + tb);
            float4 q0b = *(const float4*)(pb0 + tb + 4);
            float4 q1a = *(const float4*)(pb0 + 4096 + tb);
            float4 q1b = *(const float4*)(pb0 + 4096 + tb + 4);
            float m0v[8] = {m0a.x, m0a.y, m0a.z, m0a.w, m0b.x, m0b.y, m0b.z, m0b.w};
            float m1v[8] = {m1a.x, m1a.y, m1a.z, m1a.w, m1b.x, m1b.y, m1b.z, m1b.w};
            float q0v[8] = {q0a.x, q0a.y, q0a.z, q0a.w, q0b.x, q0b.y, q0b.z, q0b.w};
            float q1v[8] = {q1a.x, q1a.y, q1a.z, q1a.w, q1b.x, q1b.y, q1b.z, q1b.w};
#pragma unroll
            for (int q = 0; q < 2; ++q) {
                float w = wq[q];
                float kr[8], ki[8];
#pragma unroll
                for (int e = 0; e < 8; ++e) {
                    float mm = m0v[e] + (m1v[e] - m0v[e]) * w;
                    float ph = q0v[e] + (q1v[e] - q0v[e]) * w;
                    float sn, cs;
                    nsincos(ph, &sn, &cs);
                    kr[e] = mm * cs;
                    ki[e] = mm * sn;
                }
                union { unsigned u[4]; s8v v; } kR, kIp, kIn;
#pragma unroll
                for (int t = 0; t < 4; ++t) {
                    kR.u[t] = pkbf(kr[2 * t], kr[2 * t + 1]);
                    kIp.u[t] = pkbf(ki[2 * t], ki[2 * t + 1]);
                    kIn.u[t] = kIp.u[t] ^ 0x80008000u;
                }
                s8v xR = q ? xR1 : xR0;
                s8v xI = q ? xI1 : xI0;
                accR[q][ic] = __builtin_amdgcn_mfma_f32_16x16x32_bf16(xR, kR.v, accR[q][ic], 0, 0, 0);
                accR[q][ic] = __builtin_amdgcn_mfma_f32_16x16x32_bf16(xI, kIn.v, accR[q][ic], 0, 0, 0);
                accI[q][ic] = __builtin_amdgcn_mfma_f32_16x16x32_bf16(xR, kIp.v, accI[q][ic], 0, 0, 0);
                accI[q][ic] = __builtin_amdgcn_mfma_f32_16x16x32_bf16(xI, kR.v, accI[q][ic], 0, 0, 0);
            }
        }
    }

    // overlay: out[b*64+i] bf16x2 into this wave's (now dead) x regions
#pragma unroll
    for (int q = 0; q < 2; ++q) {
        int pp = wid * 2 + q;
#pragma unroll
        for (int ic = 0; ic < 4; ++ic)
#pragma unroll
            for (int e = 0; e < 4; ++e) {
                int ro = (l4 * 4 + e) * 64 + ic * 16 + l15;   // b*64 + i
                unsigned val = ((unsigned)f2bf(accI[q][ic][e]) << 16) | f2bf(accR[q][ic][e]);
                *(unsigned*)&lds[pp * REG + ro * 4] = val;
            }
    }
    __syncthreads();

    // store: 8 lanes x 8 consecutive dwords per row group (proven, no RMW amp)
#pragma unroll
    for (int k = 0; k < 32; ++k) {
        int row = k * 32 + (tid >> 3);
        unsigned v = *(const unsigned*)&lds[(tid & 7) * REG + row * 4];
        outd[(size_t)row * 8192 + p0 + (tid & 7)] = v;
    }
}

// ---------------- kernel 6: inverse FFT (radix-16) + direct coalesced output ----------------
// After pass C, thread tid gathers idx = r*512 + rev9(tid) -> holds time-samples
// n = tid*16 + rev4(r); applies activation and writes 64B contiguous (coalesced).
__global__ __launch_bounds__(512) void k_ifft(const __hip_bfloat162* __restrict__ outfft,
                                              const float* __restrict__ alpha_,
                                              float* __restrict__ out) {
    __shared__ float sRe[L];
    __shared__ float sIm[L];
    int row = blockIdx.x;          // b*64 + i
    int tid = threadIdx.x;
    float alpha = alpha_[0];
    size_t base = (size_t)row * L;

    float vr[16], vi[16];
#pragma unroll
    for (int r = 0; r < 16; ++r) {
        __hip_bfloat162 v = outfft[base + r * 512 + tid];
        vr[r] = __bfloat162float(v.x);
        vi[r] = __bfloat162float(v.y);
    }
#pragma unroll
    for (int r = 0; r < 8; ++r) {
        float sn, cs;
        nsincos(PI_F * (float)(r * 512 + tid) * (1.0f / 4096.0f), &sn, &cs);
        float ar = vr[r], ai = vi[r], br = vr[r + 8], bi = vi[r + 8];
        vr[r] = ar + br; vi[r] = ai + bi;
        float dr = ar - br, di = ai - bi;
        vr[r + 8] = dr * cs - di * sn;
        vi[r + 8] = dr * sn + di * cs;
    }
#pragma unroll
    for (int r = 0; r < 16; ++r) {
        int a = PHI(r * 512 + tid);
        sRe[a] = vr[r]; sIm[a] = vi[r];
    }
    __syncthreads();

    // pass A
    {
        int j1 = tid & 255, bA = (tid >> 8) << 12;
#pragma unroll
        for (int m = 0; m < 16; ++m) {
            int a = PHI(bA + j1 + (m << 8));
            vr[m] = sRe[a]; vi[m] = sIm[a];
        }
        float sn, cs;
        nsincos(PI_F * (float)j1 * (1.0f / 2048.0f), &sn, &cs);
        radix16<1>(vr, vi, cs, sn);
#pragma unroll
        for (int m = 0; m < 16; ++m) {
            int a = PHI(bA + j1 + (m << 8));
            sRe[a] = vr[m]; sIm[a] = vi[m];
        }
    }
    __syncthreads();
    // pass B
    {
        int j1 = tid & 15, bB = (tid >> 4) << 8;
#pragma unroll
        for (int m = 0; m < 16; ++m) {
            int a = PHI(bB + j1 + (m << 4));
            vr[m] = sRe[a]; vi[m] = sIm[a];
        }
        float sn, cs;
        nsincos(PI_F * (float)j1 * (1.0f / 128.0f), &sn, &cs);
        radix16<1>(vr, vi, cs, sn);
#pragma unroll
        for (int m = 0; m < 16; ++m) {
            int a = PHI(bB + j1 + (m << 4));
            sRe[a] = vr[m]; sIm[a] = vi[m];
        }
    }
    __syncthreads();
    // pass C
    {
        float2* f2R = (float2*)sRe;
        float2* f2I = (float2*)sIm;
#pragma unroll
        for (int m = 0; m < 8; ++m) {
            int a = PHI(tid * 16 + 2 * m) >> 1;
            float2 vR = f2R[a], vI = f2I[a];
            vr[2 * m] = vR.x; vr[2 * m + 1] = vR.y;
            vi[2 * m] = vI.x; vi[2 * m + 1] = vI.y;
        }
        radix16<1>(vr, vi, 1.0f, 0.0f);
#pragma unroll
        for (int m = 0; m < 8; ++m) {
            int a = PHI(tid * 16 + 2 * m) >> 1;
            f2R[a] = make_float2(vr[2 * m], vr[2 * m + 1]);
            f2I[a] = make_float2(vi[2 * m], vi[2 * m + 1]);
        }
    }
    __syncthreads();

    // direct gather + activation + coalesced write (64B contiguous per thread,
    // threads tile the row contiguously)
    {
        int rt = (int)(__brev((unsigned)tid) >> 23);   // rev9(tid)
        const float invN = 1.0f / (float)L;
        float o[16];
#pragma unroll
        for (int r = 0; r < 16; ++r) {
            int a = PHI(r * 512 + rt);
            int pi = (int)(__brev((unsigned)r) >> 28); // rev4(r)
            int n = tid * 16 + pi;
            o[pi] = sRe[a] * sinf(alpha * (float)n) * invN;
        }
        float* dst = out + base + (size_t)tid * 16;
#pragma unroll
        for (int k = 0; k < 4; ++k)
            *(float4*)&dst[4 * k] = make_float4(o[4 * k], o[4 * k + 1],
                                                o[4 * k + 2], o[4 * k + 3]);
    }
}

// ---------------- launch ----------------
extern "C" void kernel_launch(void* const* d_in, const int* in_sizes, int n_in,
                              void* d_out, int out_size, void* d_ws, size_t ws_size,
                              hipStream_t stream) {
    const float* xr = (const float*)d_in[0];
    const float* xi = (const float*)d_in[1];
    const float* kr = (const float*)d_in[2];
    const float* ki = (const float*)d_in[3];
    const float* alpha = (const float*)d_in[4];
    float* out = (float*)d_out;

    char* ws = (char*)d_ws;
    size_t OFFT_BYTES = (size_t)B * COUT * L * 4;
    size_t TBL_BYTES = (size_t)65 * 4096 * 4;
    unsigned* outfft_d = (unsigned*)ws;
    float* Pmag = (float*)(ws + OFFT_BYTES);
    float* Pph  = (float*)(ws + OFFT_BYTES + TBL_BYTES);
    float* pmin = (float*)(ws + OFFT_BYTES + 2 * TBL_BYTES);
    float* pmax = pmin + 1024;
    float* mmin = pmax + 1024;
    float* mmax = mmin + 16;

    unsigned* Xd = (unsigned*)d_out;   // p-blocked pair-dword x_fft; overwritten by k_ifft

    hipLaunchKernelGGL(k_reduce1, dim3(1024), dim3(256), 0, stream, xr, xi, pmin, pmax);
    hipLaunchKernelGGL(k_reduce2, dim3(16), dim3(64), 0, stream, pmin, pmax, mmin, mmax);
    hipLaunchKernelGGL(k_kstats, dim3(4096), dim3(64), 0, stream, kr, ki, Pmag, Pph);
    hipLaunchKernelGGL(k_fwd, dim3(1024), dim3(512), 0, stream, xr, xi, mmin, mmax, Xd);
    hipLaunchKernelGGL(k_gemm, dim3(1024), dim3(256), 0, stream, Xd, Pmag, Pph, outfft_d);
    hipLaunchKernelGGL(k_ifft, dim3(1024), dim3(512), 0, stream,
                       (const __hip_bfloat162*)outfft_d, alpha, out);
}

// Round 18
// 119.869 us; speedup vs baseline: 1.7465x; 1.0920x over previous
//
#include <hip/hip_runtime.h>
#include <hip/hip_fp16.h>
#include <hip/hip_bf16.h>
#include <math.h>

#define L 8192
#define LOG2L 13
#define B 16
#define CIN 64
#define COUT 64
#define KK 64

#define PI_F 3.14159265358979323846f

typedef float f4v __attribute__((ext_vector_type(4)));
typedef short s8v __attribute__((ext_vector_type(8)));

// butterfly-storage swizzle (radix-16 passes conflict-free; gather ~4-way)
__device__ __forceinline__ int PHI(int n) { return n ^ ((((n >> 5) ^ (n >> 9)) & 15) << 1); }

// native sincos (revolutions + fract range reduction)
__device__ __forceinline__ void nsincos(float ang, float* sn, float* cs) {
    float r = ang * 0.15915494309189535f;
    r = r - floorf(r);
    *sn = __builtin_amdgcn_sinf(r);
    *cs = __builtin_amdgcn_cosf(r);
}

// f32 -> bf16 bits, round-to-nearest-even
__device__ __forceinline__ unsigned short f2bf(float f) {
    unsigned u = __builtin_bit_cast(unsigned, f);
    u += 0x7FFFu + ((u >> 16) & 1u);
    return (unsigned short)(u >> 16);
}
// pack two f32 -> bf16x2 dword (round-half-up): lo = a, hi = b
__device__ __forceinline__ unsigned pkbf(float a, float b) {
    unsigned ua = __builtin_bit_cast(unsigned, a) + 0x8000u;
    unsigned ub = __builtin_bit_cast(unsigned, b) + 0x8000u;
    return (ub & 0xFFFF0000u) | (ua >> 16);
}
// unpack packed bf16x2 dword
__device__ __forceinline__ float bf_lo(unsigned u) {
    return __builtin_bit_cast(float, u << 16);
}
__device__ __forceinline__ float bf_hi(unsigned u) {
    return __builtin_bit_cast(float, u & 0xFFFF0000u);
}

// fused radix-4 butterfly (two radix-2 stages)
template<int INV>
__device__ __forceinline__ void bfly4(float& u0r, float& u0i, float& u1r, float& u1i,
                                      float& v0r, float& v0i, float& v1r, float& v1i,
                                      float w1r, float w1i, float w2r, float w2i) {
    float A0r = u0r + v0r, A0i = u0i + v0i;
    float t0r = u0r - v0r, t0i = u0i - v0i;
    float B0r = t0r * w1r - t0i * w1i, B0i = t0r * w1i + t0i * w1r;
    float A1r = u1r + v1r, A1i = u1i + v1i;
    float t1r = u1r - v1r, t1i = u1i - v1i;
    float wr = t1r * w1r - t1i * w1i, wi = t1r * w1i + t1i * w1r;
    float B1r = INV ? -wi : wi;
    float B1i = INV ? wr : -wr;
    u0r = A0r + A1r; u0i = A0i + A1i;
    float d0r = A0r - A1r, d0i = A0i - A1i;
    u1r = d0r * w2r - d0i * w2i; u1i = d0r * w2i + d0i * w2r;
    v0r = B0r + B1r; v0i = B0i + B1i;
    float d1r = B0r - B1r, d1i = B0i - B1i;
    v1r = d1r * w2r - d1i * w2i; v1i = d1r * w2i + d1i * w2r;
}

// radix-16 on 16 register points; (wc,ws) = e^{∓i pi j1/(8 len2)}
template<int INV>
__device__ __forceinline__ void radix16(float* xr, float* xi, float wc, float ws) {
    const float C8 = 0.9238795325112867f, S8 = 0.3826834323650898f, C4 = 0.7071067811865476f;
    float e1r = C8, e1i = INV ? S8 : -S8;
    float e2r = C4, e2i = INV ? C4 : -C4;
    float e3r = S8, e3i = INV ? C8 : -C8;
    float a1r[4], a1i[4], a2r[4], a2i[4];
    a1r[0] = wc;                    a1i[0] = ws;
    a1r[1] = wc * e1r - ws * e1i;   a1i[1] = wc * e1i + ws * e1r;
    a1r[2] = wc * e2r - ws * e2i;   a1i[2] = wc * e2i + ws * e2r;
    a1r[3] = wc * e3r - ws * e3i;   a1i[3] = wc * e3i + ws * e3r;
#pragma unroll
    for (int q = 0; q < 4; ++q) {
        a2r[q] = a1r[q] * a1r[q] - a1i[q] * a1i[q];
        a2i[q] = 2.f * a1r[q] * a1i[q];
    }
    float b1r = a2r[0] * a2r[0] - a2i[0] * a2i[0], b1i = 2.f * a2r[0] * a2i[0];
    float b2r = b1r * b1r - b1i * b1i, b2i = 2.f * b1r * b1i;
#pragma unroll
    for (int q = 0; q < 4; ++q)
        bfly4<INV>(xr[q], xi[q], xr[q + 4], xi[q + 4], xr[q + 8], xi[q + 8],
                   xr[q + 12], xi[q + 12], a1r[q], a1i[q], a2r[q], a2i[q]);
#pragma unroll
    for (int c = 0; c < 4; ++c)
        bfly4<INV>(xr[4 * c], xi[4 * c], xr[4 * c + 1], xi[4 * c + 1],
                   xr[4 * c + 2], xi[4 * c + 2], xr[4 * c + 3], xi[4 * c + 3],
                   b1r, b1i, b2r, b2i);
}

// ---------------- kernel 1: partial per-batch min/max of |x| ----------------
__global__ __launch_bounds__(256) void k_reduce1(const float* __restrict__ xr,
                                                 const float* __restrict__ xi,
                                                 float* __restrict__ pmin,
                                                 float* __restrict__ pmax) {
    int bid = blockIdx.x;
    int batch = bid >> 6, slice = bid & 63;
    size_t base = (size_t)batch * CIN * L + (size_t)slice * L;
    int tid = threadIdx.x;
    float mn = 3.4e38f, mx = 0.0f;
    for (int r = 0; r < 32; ++r) {
        int idx = r * 256 + tid;
        float a = xr[base + idx], b = xi[base + idx];
        float m = sqrtf(a * a + b * b);
        mn = fminf(mn, m);
        mx = fmaxf(mx, m);
    }
    __shared__ float smn[4], smx[4];
    for (int off = 32; off >= 1; off >>= 1) {
        mn = fminf(mn, __shfl_down(mn, off));
        mx = fmaxf(mx, __shfl_down(mx, off));
    }
    int wave = tid >> 6;
    if ((tid & 63) == 0) { smn[wave] = mn; smx[wave] = mx; }
    __syncthreads();
    if (tid == 0) {
        for (int w = 1; w < 4; ++w) { mn = fminf(mn, smn[w]); mx = fmaxf(mx, smx[w]); }
        pmin[bid] = mn;
        pmax[bid] = mx;
    }
}

// ---------------- kernel 2: final min/max ----------------
__global__ __launch_bounds__(64) void k_reduce2(const float* __restrict__ pmin,
                                                const float* __restrict__ pmax,
                                                float* __restrict__ mmin,
                                                float* __restrict__ mmax) {
    int b = blockIdx.x, t = threadIdx.x;
    float mn = pmin[b * 64 + t], mx = pmax[b * 64 + t];
    for (int off = 32; off >= 1; off >>= 1) {
        mn = fminf(mn, __shfl_down(mn, off));
        mx = fmaxf(mx, __shfl_down(mx, off));
    }
    if (t == 0) { mmin[b] = mn; mmax[b] = mx; }
}

// ---------------- kernel 3: kernel FFT stats, B-FRAGMENT-PACKED tables ----------------
__global__ __launch_bounds__(64) void k_kstats(const float* __restrict__ kr,
                                               const float* __restrict__ ki,
                                               float* __restrict__ Pmag,
                                               float* __restrict__ Pph) {
    int row = blockIdx.x;   // io*64 + jn
    int k = threadIdx.x;
    __shared__ float sr[64], si[64];
    sr[k] = kr[row * 64 + k];
    si[k] = ki[row * 64 + k];
    __syncthreads();
    float ar = 0.f, ai = 0.f;
    for (int n = 0; n < 64; ++n) {
        int m = (n * k) & 63;
        float ang = -2.0f * PI_F * (float)m * (1.0f / 64.0f);
        float s, c;
        __sincosf(ang, &s, &c);
        ar += sr[n] * c - si[n] * s;
        ai += sr[n] * s + si[n] * c;
    }
    float mag = sqrtf(ar * ar + ai * ai);
    float ph = atan2f(ai, ar);
    int io = row >> 6, jn = row & 63;
    int ic = io >> 4, l15 = io & 15;
    int jc = jn >> 5, hi = (jn >> 3) & 3, e = jn & 7;
    int lane = hi * 16 + l15;
    size_t off = (size_t)k * 4096 + (ic * 2 + jc) * 512 + lane * 8 + e;
    Pmag[off] = mag;
    Pph[off] = ph;
    if (k == 63) {
        Pmag[off + 4096] = mag;
        Pph[off + 4096] = ph;
    }
}

// ---------------- kernel 4: coupling + stage0-in-regs + 3 radix-16 passes (bf16 LDS) ----------------
// LDS intermediates stored as packed bf16x2 dwords (32 KB -> 4 blocks/CU, LDS ops halved).
// Pass-C output dwords ARE the X-format dwords; epilogue gathers them directly.
__global__ __launch_bounds__(512) void k_fwd(const float* __restrict__ xr,
                                             const float* __restrict__ xi,
                                             const float* __restrict__ mmin_,
                                             const float* __restrict__ mmax_,
                                             unsigned* __restrict__ Xd) {
    __shared__ unsigned sPk[L];    // 32 KB: Re bf16 (lo) | Im bf16 (hi)
    int row = blockIdx.x;          // b*64 + j
    int b = row >> 6;
    int tid = threadIdx.x;
    float mmin = mmin_[b], mmax = mmax_[b];
    float span = mmax - mmin;
    float invden = 1.0f / (span + 1e-10f);
    size_t base = (size_t)row * L;

    float vr[16], vi[16];
    // coupling via rsqrt (no sqrt+div): m = m2*rinv, scale = mc*rinv
#pragma unroll
    for (int r = 0; r < 16; ++r) {
        int idx = r * 512 + tid;
        float a = xr[base + idx], c = xi[base + idx];
        float m2 = a * a + c * c;
        float rinv = (m2 > 0.0f) ? __builtin_amdgcn_rsqf(m2) : 0.0f;
        float m = m2 * rinv;
        float xn = (m - mmin) * invden;
#pragma unroll
        for (int it = 0; it < 5; ++it) xn = 3.8f * xn * (1.0f - xn);
        float mc = xn * span + mmin;
        float scale = mc * rinv;
        vr[r] = a * scale;
        vi[r] = c * scale;
    }
    // stage 0 (len 4096): W(r) = W0 * E^r, E = e^{-i pi/8}, one sincos total
    {
        const float ER = 0.9238795325112867f, EI = -0.3826834323650898f;
        float wr_, wi_;
        nsincos(-PI_F * (float)tid * (1.0f / 4096.0f), &wi_, &wr_);
#pragma unroll
        for (int r = 0; r < 8; ++r) {
            float ar = vr[r], ai = vi[r], br = vr[r + 8], bi = vi[r + 8];
            vr[r] = ar + br; vi[r] = ai + bi;
            float dr = ar - br, di = ai - bi;
            vr[r + 8] = dr * wr_ - di * wi_;
            vi[r + 8] = dr * wi_ + di * wr_;
            float nr = wr_ * ER - wi_ * EI;
            wi_ = wr_ * EI + wi_ * ER;
            wr_ = nr;
        }
    }
#pragma unroll
    for (int r = 0; r < 16; ++r)
        sPk[PHI(r * 512 + tid)] = pkbf(vr[r], vi[r]);
    __syncthreads();

    // pass A: stages 1-4, len2=256
    {
        int j1 = tid & 255, bA = (tid >> 8) << 12;
#pragma unroll
        for (int m = 0; m < 16; ++m) {
            unsigned u = sPk[PHI(bA + j1 + (m << 8))];
            vr[m] = bf_lo(u); vi[m] = bf_hi(u);
        }
        float sn, cs;
        nsincos(-PI_F * (float)j1 * (1.0f / 2048.0f), &sn, &cs);
        radix16<0>(vr, vi, cs, sn);
#pragma unroll
        for (int m = 0; m < 16; ++m)
            sPk[PHI(bA + j1 + (m << 8))] = pkbf(vr[m], vi[m]);
    }
    __syncthreads();
    // pass B: stages 5-8, len2=16
    {
        int j1 = tid & 15, bB = (tid >> 4) << 8;
#pragma unroll
        for (int m = 0; m < 16; ++m) {
            unsigned u = sPk[PHI(bB + j1 + (m << 4))];
            vr[m] = bf_lo(u); vi[m] = bf_hi(u);
        }
        float sn, cs;
        nsincos(-PI_F * (float)j1 * (1.0f / 128.0f), &sn, &cs);
        radix16<0>(vr, vi, cs, sn);
#pragma unroll
        for (int m = 0; m < 16; ++m)
            sPk[PHI(bB + j1 + (m << 4))] = pkbf(vr[m], vi[m]);
    }
    __syncthreads();
    // pass C: stages 9-12, len2=1 (even-odd pairs adjacent under PHI -> uint2 ops)
    {
        uint2* s2 = (uint2*)sPk;
#pragma unroll
        for (int m = 0; m < 8; ++m) {
            int a = PHI(tid * 16 + 2 * m) >> 1;
            uint2 u2 = s2[a];
            vr[2 * m] = bf_lo(u2.x); vi[2 * m] = bf_hi(u2.x);
            vr[2 * m + 1] = bf_lo(u2.y); vi[2 * m + 1] = bf_hi(u2.y);
        }
        radix16<0>(vr, vi, 1.0f, 0.0f);
#pragma unroll
        for (int m = 0; m < 8; ++m) {
            int a = PHI(tid * 16 + 2 * m) >> 1;
            s2[a] = make_uint2(pkbf(vr[2 * m], vi[2 * m]),
                               pkbf(vr[2 * m + 1], vi[2 * m + 1]));
        }
    }
    __syncthreads();

    // direct gather: dwords are already X-format (R | I<<16)
    {
        int rt = (int)(__brev((unsigned)tid) >> 23);   // rev9(tid)
        unsigned o16[16];
#pragma unroll
        for (int r = 0; r < 16; ++r) {
            int pi = (int)(__brev((unsigned)r) >> 28); // rev4(r)
            o16[pi] = sPk[PHI(r * 512 + rt)];
        }
        size_t ob = (size_t)tid * 16384 + (size_t)row * 16;
#pragma unroll
        for (int k = 0; k < 4; ++k)
            *(uint4*)&Xd[ob + 4 * k] = make_uint4(o16[4 * k], o16[4 * k + 1],
                                                  o16[4 * k + 2], o16[4 * k + 3]);
    }
}

// ---------------- kernel 5: MFMA complex GEMM over frequencies (unchanged) ----------------
#define PBG 8
#define REG 4624   // bytes per p-region: 2 planes x (16 rows x 144B), 16-aligned
__global__ __launch_bounds__(256) void k_gemm(const unsigned* __restrict__ X,
                                              const float* __restrict__ Pmag,
                                              const float* __restrict__ Pph,
                                              unsigned* __restrict__ outd) {
    __shared__ uint4 ldsbuf[(PBG * REG) / 16];   // 36,992 B
    char* lds = (char*)ldsbuf;
    int tid = threadIdx.x;
    int bid = blockIdx.x;   // 1024
    int pwin = ((bid & 7) << 7) + (bid >> 3);   // XCD-contiguous; half-siblings adjacent
    int p0 = pwin * PBG;
    int half = pwin & 1;
    const unsigned* src = X + (size_t)(pwin >> 1) * 16384 + half * 8;

    // stage: dense reads (2 x 16B per 64B row-chunk), de-interleave to planar
#pragma unroll
    for (int k = 0; k < 8; ++k) {
        int u = k * 256 + tid;              // 0..2047
        int row = u >> 1;                   // b*64 + j
        int g = u & 1;
        uint4 v = *(const uint4*)&src[(size_t)row * 16 + g * 4];
        int base = (row >> 6) * 144 + (row & 63) * 2;
        unsigned dw[4] = {v.x, v.y, v.z, v.w};
#pragma unroll
        for (int c = 0; c < 4; ++c) {
            int pl = g * 4 + c;
            *(unsigned short*)&lds[pl * REG + base] = (unsigned short)(dw[c] & 0xFFFFu);
            *(unsigned short*)&lds[pl * REG + 2304 + base] = (unsigned short)(dw[c] >> 16);
        }
    }
    __syncthreads();

    int lane = tid & 63, wid = tid >> 6;
    int l15 = lane & 15, l4 = lane >> 4;

    int pA = p0 + wid * 2;
    float posA = ((float)pA + 0.5f) * (1.0f / 128.0f) - 0.5f;
    posA = fmaxf(posA, 0.0f);
    int i0k = (int)posA;
    bool clampv = (i0k >= KK - 1);
    float wq[2];
#pragma unroll
    for (int q = 0; q < 2; ++q) {
        float pos = ((float)(pA + q) + 0.5f) * (1.0f / 128.0f) - 0.5f;
        pos = fmaxf(pos, 0.0f);
        wq[q] = clampv ? 0.0f : (pos - (float)i0k);
    }
    const float* mb0 = Pmag + (size_t)i0k * 4096;
    const float* pb0 = Pph + (size_t)i0k * 4096;

    f4v accR[2][4], accI[2][4];
#pragma unroll
    for (int q = 0; q < 2; ++q)
#pragma unroll
        for (int ic = 0; ic < 4; ++ic) { accR[q][ic] = (f4v)0.0f; accI[q][ic] = (f4v)0.0f; }

#pragma unroll
    for (int jc = 0; jc < 2; ++jc) {
        int jb2 = (jc * 32 + l4 * 8) * 2;    // byte offset of A-frag j-slice
        s8v xR0 = *(const s8v*)&lds[(wid * 2 + 0) * REG + l15 * 144 + jb2];
        s8v xI0 = *(const s8v*)&lds[(wid * 2 + 0) * REG + 2304 + l15 * 144 + jb2];
        s8v xR1 = *(const s8v*)&lds[(wid * 2 + 1) * REG + l15 * 144 + jb2];
        s8v xI1 = *(const s8v*)&lds[(wid * 2 + 1) * REG + 2304 + l15 * 144 + jb2];
#pragma unroll
        for (int ic = 0; ic < 4; ++ic) {
            int tb = (ic * 2 + jc) * 512 + lane * 8;   // coalesced 2KB wave burst
            float4 m0a = *(const float4*)(mb0 + tb);
            float4 m0b = *(const float4*)(mb0 + tb + 4);
            float4 m1a = *(const float4*)(mb0 + 4096 + tb);
            float4 m1b = *(const float4*)(mb0 + 4096 + tb + 4);
            float4 q0a = *(const float4*)(pb0 + tb);
            float4 q0b = *(const float4*)(pb0 + tb + 4);
            float4 q1a = *(const float4*)(pb0 + 4096 + tb);
            float4 q1b = *(const float4*)(pb0 + 4096 + tb + 4);
            float m0v[8] = {m0a.x, m0a.y, m0a.z, m0a.w, m0b.x, m0b.y, m0b.z, m0b.w};
            float m1v[8] = {m1a.x, m1a.y, m1a.z, m1a.w, m1b.x, m1b.y, m1b.z, m1b.w};
            float q0v[8] = {q0a.x, q0a.y, q0a.z, q0a.w, q0b.x, q0b.y, q0b.z, q0b.w};
            float q1v[8] = {q1a.x, q1a.y, q1a.z, q1a.w, q1b.x, q1b.y, q1b.z, q1b.w};
#pragma unroll
            for (int q = 0; q < 2; ++q) {
                float w = wq[q];
                float kr[8], ki[8];
#pragma unroll
                for (int e = 0; e < 8; ++e) {
                    float mm = m0v[e] + (m1v[e] - m0v[e]) * w;
                    float ph = q0v[e] + (q1v[e] - q0v[e]) * w;
                    float sn, cs;
                    nsincos(ph, &sn, &cs);
                    kr[e] = mm * cs;
                    ki[e] = mm * sn;
                }
                union { unsigned u[4]; s8v v; } kR, kIp, kIn;
#pragma unroll
                for (int t = 0; t < 4; ++t) {
                    kR.u[t] = pkbf(kr[2 * t], kr[2 * t + 1]);
                    kIp.u[t] = pkbf(ki[2 * t], ki[2 * t + 1]);
                    kIn.u[t] = kIp.u[t] ^ 0x80008000u;
                }
                s8v xR = q ? xR1 : xR0;
                s8v xI = q ? xI1 : xI0;
                accR[q][ic] = __builtin_amdgcn_mfma_f32_16x16x32_bf16(xR, kR.v, accR[q][ic], 0, 0, 0);
                accR[q][ic] = __builtin_amdgcn_mfma_f32_16x16x32_bf16(xI, kIn.v, accR[q][ic], 0, 0, 0);
                accI[q][ic] = __builtin_amdgcn_mfma_f32_16x16x32_bf16(xR, kIp.v, accI[q][ic], 0, 0, 0);
                accI[q][ic] = __builtin_amdgcn_mfma_f32_16x16x32_bf16(xI, kR.v, accI[q][ic], 0, 0, 0);
            }
        }
    }

    // overlay: out[b*64+i] bf16x2 into this wave's (now dead) x regions
#pragma unroll
    for (int q = 0; q < 2; ++q) {
        int pp = wid * 2 + q;
#pragma unroll
        for (int ic = 0; ic < 4; ++ic)
#pragma unroll
            for (int e = 0; e < 4; ++e) {
                int ro = (l4 * 4 + e) * 64 + ic * 16 + l15;   // b*64 + i
                unsigned val = ((unsigned)f2bf(accI[q][ic][e]) << 16) | f2bf(accR[q][ic][e]);
                *(unsigned*)&lds[pp * REG + ro * 4] = val;
            }
    }
    __syncthreads();

    // store: 8 lanes x 8 consecutive dwords per row group (proven, no RMW amp)
#pragma unroll
    for (int k = 0; k < 32; ++k) {
        int row = k * 32 + (tid >> 3);
        unsigned v = *(const unsigned*)&lds[(tid & 7) * REG + row * 4];
        outd[(size_t)row * 8192 + p0 + (tid & 7)] = v;
    }
}

// ---------------- kernel 6: inverse FFT (radix-16, f32 LDS) + phasor activation ----------------
__global__ __launch_bounds__(512) void k_ifft(const __hip_bfloat162* __restrict__ outfft,
                                              const float* __restrict__ alpha_,
                                              float* __restrict__ out) {
    __shared__ float sRe[L];
    __shared__ float sIm[L];
    int row = blockIdx.x;          // b*64 + i
    int tid = threadIdx.x;
    float alpha = alpha_[0];
    size_t base = (size_t)row * L;

    float vr[16], vi[16];
#pragma unroll
    for (int r = 0; r < 16; ++r) {
        __hip_bfloat162 v = outfft[base + r * 512 + tid];
        vr[r] = __bfloat162float(v.x);
        vi[r] = __bfloat162float(v.y);
    }
    // stage 0, positive twiddles via phasor recurrence (E = e^{+i pi/8})
    {
        const float ER = 0.9238795325112867f, EI = 0.3826834323650898f;
        float wr_, wi_;
        nsincos(PI_F * (float)tid * (1.0f / 4096.0f), &wi_, &wr_);
#pragma unroll
        for (int r = 0; r < 8; ++r) {
            float ar = vr[r], ai = vi[r], br = vr[r + 8], bi = vi[r + 8];
            vr[r] = ar + br; vi[r] = ai + bi;
            float dr = ar - br, di = ai - bi;
            vr[r + 8] = dr * wr_ - di * wi_;
            vi[r + 8] = dr * wi_ + di * wr_;
            float nr = wr_ * ER - wi_ * EI;
            wi_ = wr_ * EI + wi_ * ER;
            wr_ = nr;
        }
    }
#pragma unroll
    for (int r = 0; r < 16; ++r) {
        int a = PHI(r * 512 + tid);
        sRe[a] = vr[r]; sIm[a] = vi[r];
    }
    __syncthreads();

    // pass A
    {
        int j1 = tid & 255, bA = (tid >> 8) << 12;
#pragma unroll
        for (int m = 0; m < 16; ++m) {
            int a = PHI(bA + j1 + (m << 8));
            vr[m] = sRe[a]; vi[m] = sIm[a];
        }
        float sn, cs;
        nsincos(PI_F * (float)j1 * (1.0f / 2048.0f), &sn, &cs);
        radix16<1>(vr, vi, cs, sn);
#pragma unroll
        for (int m = 0; m < 16; ++m) {
            int a = PHI(bA + j1 + (m << 8));
            sRe[a] = vr[m]; sIm[a] = vi[m];
        }
    }
    __syncthreads();
    // pass B
    {
        int j1 = tid & 15, bB = (tid >> 4) << 8;
#pragma unroll
        for (int m = 0; m < 16; ++m) {
            int a = PHI(bB + j1 + (m << 4));
            vr[m] = sRe[a]; vi[m] = sIm[a];
        }
        float sn, cs;
        nsincos(PI_F * (float)j1 * (1.0f / 128.0f), &sn, &cs);
        radix16<1>(vr, vi, cs, sn);
#pragma unroll
        for (int m = 0; m < 16; ++m) {
            int a = PHI(bB + j1 + (m << 4));
            sRe[a] = vr[m]; sIm[a] = vi[m];
        }
    }
    __syncthreads();
    // pass C
    {
        float2* f2R = (float2*)sRe;
        float2* f2I = (float2*)sIm;
#pragma unroll
        for (int m = 0; m < 8; ++m) {
            int a = PHI(tid * 16 + 2 * m) >> 1;
            float2 vR = f2R[a], vI = f2I[a];
            vr[2 * m] = vR.x; vr[2 * m + 1] = vR.y;
            vi[2 * m] = vI.x; vi[2 * m + 1] = vI.y;
        }
        radix16<1>(vr, vi, 1.0f, 0.0f);
#pragma unroll
        for (int m = 0; m < 8; ++m) {
            int a = PHI(tid * 16 + 2 * m) >> 1;
            f2R[a] = make_float2(vr[2 * m], vr[2 * m + 1]);
            f2I[a] = make_float2(vi[2 * m], vi[2 * m + 1]);
        }
    }
    __syncthreads();

    // direct gather + rotating-phasor activation + coalesced write
    {
        int rt = (int)(__brev((unsigned)tid) >> 23);   // rev9(tid)
        const float invN = 1.0f / (float)L;
        float t16[16];
#pragma unroll
        for (int r = 0; r < 16; ++r) {
            int a = PHI(r * 512 + rt);
            int pi = (int)(__brev((unsigned)r) >> 28); // rev4(r)
            t16[pi] = sRe[a];
        }
        float sA, cA, s1, c1;
        nsincos(alpha * (float)(tid * 16), &sA, &cA);
        nsincos(alpha, &s1, &c1);
        float o[16];
#pragma unroll
        for (int pi = 0; pi < 16; ++pi) {
            o[pi] = t16[pi] * sA * invN;
            float ns = sA * c1 + cA * s1;
            cA = cA * c1 - sA * s1;
            sA = ns;
        }
        float* dst = out + base + (size_t)tid * 16;
#pragma unroll
        for (int k = 0; k < 4; ++k)
            *(float4*)&dst[4 * k] = make_float4(o[4 * k], o[4 * k + 1],
                                                o[4 * k + 2], o[4 * k + 3]);
    }
}

// ---------------- launch ----------------
extern "C" void kernel_launch(void* const* d_in, const int* in_sizes, int n_in,
                              void* d_out, int out_size, void* d_ws, size_t ws_size,
                              hipStream_t stream) {
    const float* xr = (const float*)d_in[0];
    const float* xi = (const float*)d_in[1];
    const float* kr = (const float*)d_in[2];
    const float* ki = (const float*)d_in[3];
    const float* alpha = (const float*)d_in[4];
    float* out = (float*)d_out;

    char* ws = (char*)d_ws;
    size_t OFFT_BYTES = (size_t)B * COUT * L * 4;
    size_t TBL_BYTES = (size_t)65 * 4096 * 4;
    unsigned* outfft_d = (unsigned*)ws;
    float* Pmag = (float*)(ws + OFFT_BYTES);
    float* Pph  = (float*)(ws + OFFT_BYTES + TBL_BYTES);
    float* pmin = (float*)(ws + OFFT_BYTES + 2 * TBL_BYTES);
    float* pmax = pmin + 1024;
    float* mmin = pmax + 1024;
    float* mmax = mmin + 16;

    unsigned* Xd = (unsigned*)d_out;   // p-blocked pair-dword x_fft; overwritten by k_ifft

    hipLaunchKernelGGL(k_reduce1, dim3(1024), dim3(256), 0, stream, xr, xi, pmin, pmax);
    hipLaunchKernelGGL(k_reduce2, dim3(16), dim3(64), 0, stream, pmin, pmax, mmin, mmax);
    hipLaunchKernelGGL(k_kstats, dim3(4096), dim3(64), 0, stream, kr, ki, Pmag, Pph);
    hipLaunchKernelGGL(k_fwd, dim3(1024), dim3(512), 0, stream, xr, xi, mmin, mmax, Xd);
    hipLaunchKernelGGL(k_gemm, dim3(1024), dim3(256), 0, stream, Xd, Pmag, Pph, outfft_d);
    hipLaunchKernelGGL(k_ifft, dim3(1024), dim3(512), 0, stream,
                       (const __hip_bfloat162*)outfft_d, alpha, out);
}